// Round 3
// baseline (2111.692 us; speedup 1.0000x reference)
//
#include <hip/hip_runtime.h>
#include <hip/hip_bf16.h>
#include <math.h>

// Problem constants
#define Bb 32
#define Dd 512
#define Ss 512      // NC + Hs*Ws
#define NHh 8
#define DHh 64
#define MLPm 2048
#define NCc 256
#define INNERi 512
#define Mrows (Bb*Ss)   // 16384

typedef __bf16 bf16x8 __attribute__((ext_vector_type(8)));
typedef float floatx4 __attribute__((ext_vector_type(4)));

__device__ __forceinline__ void load_lds16(const void* g, void* l) {
  __builtin_amdgcn_global_load_lds(
      (__attribute__((address_space(1))) void*)(g),
      (__attribute__((address_space(3))) void*)(l), 16, 0, 0);
}

// XOR-swizzled LDS addressing for 64-elem bf16 rows: logical (row, seg8)
// stored at row*64 + ((seg ^ (row&7))<<3). b128 frag reads spread banks.
__device__ __forceinline__ int swz(int row, int seg) {
  return row * 64 + (((seg) ^ (row & 7)) << 3);
}

// ---------------------------------------------------------------------------
// Tiled transpose + fp32->bf16 downcast: in (K,N) fp32 -> out (N,K) bf16
// ---------------------------------------------------------------------------
__global__ void transpose_w(const float* __restrict__ in, __hip_bfloat16* __restrict__ out,
                            int K, int N, size_t in_ls, size_t out_ls)
{
  __shared__ float tile[32][33];
  in  += (size_t)blockIdx.z * in_ls;
  out += (size_t)blockIdx.z * out_ls;
  int n0 = blockIdx.x * 32, k0 = blockIdx.y * 32;
  int tx = threadIdx.x;
  #pragma unroll
  for (int i = threadIdx.y; i < 32; i += 8)
    tile[i][tx] = in[(size_t)(k0 + i) * N + n0 + tx];
  __syncthreads();
  #pragma unroll
  for (int i = threadIdx.y; i < 32; i += 8)
    out[(size_t)(n0 + i) * K + k0 + tx] = __float2bfloat16(tile[tx][i]);
}

// ---------------------------------------------------------------------------
// Prologue: build x[b,s,:] (slots+slot_pos | z^T+pos), then LayerNorm(norm_w/b)
// ---------------------------------------------------------------------------
__global__ void prologue_kernel(const float* __restrict__ z, const float* __restrict__ slots,
                                const float* __restrict__ pos, const float* __restrict__ spos,
                                const float* __restrict__ nw, const float* __restrict__ nb,
                                float* __restrict__ x)
{
  int row = blockIdx.x;            // b*S + s
  int b = row >> 9, s = row & 511;
  int lane = threadIdx.x;
  float v[8];
  float sum = 0.f;
  #pragma unroll
  for (int j = 0; j < 8; ++j) {
    int d = lane + j * 64;
    float t;
    if (s < NCc) t = slots[((size_t)b * NCc + s) * Dd + d] + spos[(size_t)s * Dd + d];
    else {
      int sp = s - NCc;
      t = z[((size_t)b * Dd + d) * 256 + sp] + pos[(size_t)sp * Dd + d];
    }
    v[j] = t; sum += t;
  }
  #pragma unroll
  for (int o = 32; o; o >>= 1) sum += __shfl_xor(sum, o);
  float mean = sum * (1.f / Dd);
  float vs = 0.f;
  #pragma unroll
  for (int j = 0; j < 8; ++j) { float d = v[j] - mean; vs += d * d; }
  #pragma unroll
  for (int o = 32; o; o >>= 1) vs += __shfl_xor(vs, o);
  float rs = rsqrtf(vs * (1.f / Dd) + 1e-5f);
  #pragma unroll
  for (int j = 0; j < 8; ++j) {
    int d = lane + j * 64;
    x[(size_t)row * Dd + d] = (v[j] - mean) * rs * nw[d] + nb[d];
  }
}

// ---------------------------------------------------------------------------
// LayerNorm: x fp32 (rows,512) -> y bf16
// ---------------------------------------------------------------------------
__global__ void ln_kernel(const float* __restrict__ x, const float* __restrict__ w,
                          const float* __restrict__ b, __hip_bfloat16* __restrict__ y)
{
  int row = blockIdx.x * 4 + (threadIdx.x >> 6);
  int lane = threadIdx.x & 63;
  const float* xr = x + (size_t)row * Dd;
  float v[8];
  float sum = 0.f;
  #pragma unroll
  for (int j = 0; j < 8; ++j) { v[j] = xr[lane + j * 64]; sum += v[j]; }
  #pragma unroll
  for (int o = 32; o; o >>= 1) sum += __shfl_xor(sum, o);
  float mean = sum * (1.f / Dd);
  float vs = 0.f;
  #pragma unroll
  for (int j = 0; j < 8; ++j) { float d = v[j] - mean; vs += d * d; }
  #pragma unroll
  for (int o = 32; o; o >>= 1) vs += __shfl_xor(vs, o);
  float rs = rsqrtf(vs * (1.f / Dd) + 1e-5f);
  #pragma unroll
  for (int j = 0; j < 8; ++j) {
    int d = lane + j * 64;
    y[(size_t)row * Dd + d] = __float2bfloat16((v[j] - mean) * rs * w[d] + b[d]);
  }
}

// ---------------------------------------------------------------------------
// bf16 MFMA GEMM (128x128 tile, m97 structure): C(M,N) = A(M,K) @ Bt(N,K)^T
// Kept for the N=512 GEMMs (out-proj, mlp2).
// ---------------------------------------------------------------------------
template <int MODE>
__global__ __launch_bounds__(256, 2)
void gemm_bt(const __hip_bfloat16* __restrict__ A, const __hip_bfloat16* __restrict__ Bt,
             const float* __restrict__ bias, const float* __restrict__ res,
             void* __restrict__ Out, int M, int N, int K)
{
  constexpr int BM = 128, BN = 128, BK = 64;
  __shared__ __align__(16) __hip_bfloat16 As[BM * BK];
  __shared__ __align__(16) __hip_bfloat16 Bs[BN * BK];
  const int tid = threadIdx.x;
  const int lane = tid & 63;
  const int wave = tid >> 6;

  const int NBLK = N >> 7;
  const int bid = blockIdx.x;
  const int xcd = bid & 7;
  const int j = bid >> 3;
  const int nb = j % NBLK;
  const int mt = xcd + ((j / NBLK) << 3);
  const int m0 = mt << 7;
  const int n0 = nb << 7;

  const int wm = (wave & 1) * 64;
  const int wn = (wave >> 1) * 64;
  const int quad = lane >> 4;
  const int lrow = lane & 15;

  floatx4 acc[4][4];
  #pragma unroll
  for (int i = 0; i < 4; ++i)
    #pragma unroll
    for (int jj = 0; jj < 4; ++jj) {
      floatx4 z4 = {0.f, 0.f, 0.f, 0.f};
      acc[i][jj] = z4;
    }

  for (int k0 = 0; k0 < K; k0 += BK) {
    #pragma unroll
    for (int it = 0; it < 4; ++it) {
      int c = it * 256 + tid;
      int row = c >> 3, seg = (c & 7) ^ (row & 7);
      load_lds16(A + (size_t)(m0 + row) * K + k0 + seg * 8, As + c * 8);
    }
    #pragma unroll
    for (int it = 0; it < 4; ++it) {
      int c = it * 256 + tid;
      int row = c >> 3, seg = (c & 7) ^ (row & 7);
      load_lds16(Bt + (size_t)(n0 + row) * K + k0 + seg * 8, Bs + c * 8);
    }
    __syncthreads();

    #pragma unroll
    for (int k1 = 0; k1 < BK; k1 += 32) {
      const int s0 = k1 >> 3;   // 0 or 4
      bf16x8 a[4], b[4];
      #pragma unroll
      for (int i = 0; i < 4; ++i)
        a[i] = *reinterpret_cast<const bf16x8*>(&As[swz(wm + i * 16 + lrow, s0 + quad)]);
      #pragma unroll
      for (int i = 0; i < 4; ++i)
        b[i] = *reinterpret_cast<const bf16x8*>(&Bs[swz(wn + i * 16 + lrow, s0 + quad)]);
      #pragma unroll
      for (int mi = 0; mi < 4; ++mi)
        #pragma unroll
        for (int ni = 0; ni < 4; ++ni)
          acc[mi][ni] = __builtin_amdgcn_mfma_f32_16x16x32_bf16(a[mi], b[ni], acc[mi][ni], 0, 0, 0);
    }
    __syncthreads();
  }

  #pragma unroll
  for (int mi = 0; mi < 4; ++mi) {
    #pragma unroll
    for (int r = 0; r < 4; ++r) {
      int gm = m0 + wm + mi * 16 + quad * 4 + r;
      #pragma unroll
      for (int ni = 0; ni < 4; ++ni) {
        int gn = n0 + wn + ni * 16 + lrow;
        float v = acc[mi][ni][r];
        size_t oi = (size_t)gm * N + gn;
        if (MODE == 0) {
          ((__hip_bfloat16*)Out)[oi] = __float2bfloat16(v);
        } else if (MODE == 1) {
          ((float*)Out)[oi] = v + bias[gn] + res[oi];
        } else {
          float t = v + bias[gn];
          float g = 0.5f * t * (1.0f + erff(t * 0.70710678118654752f));
          ((__hip_bfloat16*)Out)[oi] = __float2bfloat16(g);
        }
      }
    }
  }
}

// ---------------------------------------------------------------------------
// 256x256 bf16 MFMA GEMM, round-3: TWO fat phases per K-tile (was 4 thin).
// Round-2 diagnosis: phase = 2740 cyc of which ~1300 was per-phase fixed
// overhead (2 barriers, lgkm resync, stage VALU, wait residue) that cannot
// overlap anything at 1 block/CU (224 unified regs -> no co-residency).
// Fix: amortize — 32 MFMA + 16(or 8) ds_read per phase, 2 barriers/phase,
// 4 barriers per K-tile instead of 8.
//   P0(t): stage A(t+1) both halves [4 glds]; ds_read B(t)x8 + A(t).mh0 x8;
//          bar; lgkm0; 32 MFMA -> acc[0]; bar
//   P1(t): stage B(t+2) both halves [4 glds]; ds_read A(t).mh1 x8;
//          bar; lgkm0; 32 MFMA -> acc[1]; vmcnt(4); bar
// Slot lifetime audit: B(t) slots last read in P0 (regs cached through P1);
// A(t) slots last read in P1. Stage of a slot is issued only after the
// closing barrier of the phase whose pre-MFMA lgkm(0) proved all waves'
// reads of that slot completed — fully fenced.
// vmcnt ledger (4 loads per stage-pair, per wave): at end of P1(t)
// outstanding = B(t+1):4, A(t+1):4, B(t+2):4 = 12; vmcnt(4) forces
// B(t+1)+A(t+1) landed (needed by P0(t+1)), leaves B(t+2) in flight.
// Prologue B(0),A(0),B(1) + vmcnt(4) reproduces steady state exactly.
// ---------------------------------------------------------------------------
#define GBAR()    asm volatile("s_barrier" ::: "memory")
#define GWAIT4()  asm volatile("s_waitcnt vmcnt(4)" ::: "memory")
#define GWAIT0()  asm volatile("s_waitcnt vmcnt(0)" ::: "memory")
#define LGKM0()   do { asm volatile("s_waitcnt lgkmcnt(0)" ::: "memory"); \
                       __builtin_amdgcn_sched_barrier(0); } while (0)
#define DSRO(d,a,OFFSTR) asm volatile("ds_read_b128 %0, %1 offset:" OFFSTR \
                                      : "=v"(d) : "v"(a))

template <int MODE>   // 0: bf16 out, no bias; 2: bf16 out = gelu(acc + bias)
__global__ __launch_bounds__(512, 2)
void gemm256(const __hip_bfloat16* __restrict__ A, const __hip_bfloat16* __restrict__ Bt,
             const float* __restrict__ bias, void* __restrict__ Out,
             int M, int N, int K)
{
  extern __shared__ __hip_bfloat16 lds[];   // 65536 bf16 = 128 KiB
  const int tid  = threadIdx.x;
  const int lane = tid & 63;
  const int wave = tid >> 6;
  const int wm = wave >> 2, wn = wave & 3;
  const int quad = lane >> 4, lrow = lane & 15;

  // bijective XCD swizzle (m204), then row-major (mt, nt)
  const int NBN = N >> 8;
  const int nwg = gridDim.x;
  const int bid = blockIdx.x;
  const int qq = nwg >> 3, rr = nwg & 7;
  const int xcd = bid & 7, oin = bid >> 3;
  const int wg = (xcd < rr ? xcd * (qq + 1) : rr * (qq + 1) + (xcd - rr) * qq) + oin;
  const int m0 = (wg / NBN) << 8;
  const int n0 = (wg % NBN) << 8;
  const int NT = K >> 6;

  // staging: slot = 256 rows x 32 cols bf16 (16 KB); global seg XOR-permuted
  // so lane-linear LDS lands swizzled.
  const int srow = tid >> 2;
  const int sseg = (tid & 3) ^ ((tid >> 3) & 3);
  const __hip_bfloat16* gA = A  + (size_t)(m0 + srow) * K + sseg * 8;
  const __hip_bfloat16* gB = Bt + (size_t)(n0 + srow) * K + sseg * 8;
  const size_t gstep = (size_t)128 * K;

  __hip_bfloat16* const Abase = lds;
  __hip_bfloat16* const Bbase = lds + 32768;

  // stage BOTH K-halves of tile t (4 glds/thread)
  auto stageApair = [&](int t) {
    int ts = t < NT ? t : NT - 1;            // clamp source, keep count uniform
    int kb = ts * 64;
    __hip_bfloat16* d = Abase + ((t & 1) * 2) * 8192 + tid * 8;
    load_lds16(gA + kb, d);                       // kh0 rows 0..127
    load_lds16(gA + gstep + kb, d + 4096);        // kh0 rows 128..255
    load_lds16(gA + kb + 32, d + 8192);           // kh1 rows 0..127
    load_lds16(gA + gstep + kb + 32, d + 12288);  // kh1 rows 128..255
  };
  auto stageBpair = [&](int t) {
    int ts = t < NT ? t : NT - 1;
    int kb = ts * 64;
    __hip_bfloat16* d = Bbase + ((t & 1) * 2) * 8192 + tid * 8;
    load_lds16(gB + kb, d);
    load_lds16(gB + gstep + kb, d + 4096);
    load_lds16(gB + kb + 32, d + 8192);
    load_lds16(gB + gstep + kb + 32, d + 12288);
  };

  floatx4 acc[2][4][4];
  #pragma unroll
  for (int mh = 0; mh < 2; ++mh)
    #pragma unroll
    for (int mi = 0; mi < 4; ++mi)
      #pragma unroll
      for (int ni = 0; ni < 4; ++ni) {
        floatx4 z4 = {0.f, 0.f, 0.f, 0.f};
        acc[mh][mi][ni] = z4;
      }

  // raw 32-bit LDS byte addresses for asm ds_read
  const uint32_t ldsA = (uint32_t)(size_t)(__attribute__((address_space(3))) void*)Abase;
  const uint32_t ldsB = (uint32_t)(size_t)(__attribute__((address_space(3))) void*)Bbase;
  const uint32_t rsegb = (uint32_t)((quad ^ ((lrow >> 1) & 3)) << 4);
  const uint32_t arow_b = (uint32_t)((wm * 128 + lrow) * 64) + rsegb;
  const uint32_t brow_b = (uint32_t)((wn * 64 + lrow) * 64) + rsegb;

  // prologue (steady-state issue history): B(0), A(0), B(1)
  stageBpair(0); stageApair(0); stageBpair(1);
  GWAIT4();           // B(0), A(0) landed; B(1) in flight
  GBAR();

  bf16x8 af[2][4], bfr[2][4];
  for (int t = 0; t < NT; ++t) {
    const uint32_t aA = ldsA + (uint32_t)((t & 1) * 32768) + arow_b;
    const uint32_t bA = ldsB + (uint32_t)((t & 1) * 32768) + brow_b;

    // ---- P0: B(t) x8, A(t).mh0 x8, 32 MFMA -> acc[0] ----
    stageApair(t + 1);
    DSRO(bfr[0][0], bA, "0");     DSRO(bfr[0][1], bA, "1024");
    DSRO(bfr[0][2], bA, "2048");  DSRO(bfr[0][3], bA, "3072");
    DSRO(bfr[1][0], bA, "16384"); DSRO(bfr[1][1], bA, "17408");
    DSRO(bfr[1][2], bA, "18432"); DSRO(bfr[1][3], bA, "19456");
    DSRO(af[0][0], aA, "0");      DSRO(af[0][1], aA, "1024");
    DSRO(af[0][2], aA, "2048");   DSRO(af[0][3], aA, "3072");
    DSRO(af[1][0], aA, "16384");  DSRO(af[1][1], aA, "17408");
    DSRO(af[1][2], aA, "18432");  DSRO(af[1][3], aA, "19456");
    GBAR();
    LGKM0();
    __builtin_amdgcn_s_setprio(1);
    #pragma unroll
    for (int ks = 0; ks < 2; ++ks)
      #pragma unroll
      for (int mi = 0; mi < 4; ++mi)
        #pragma unroll
        for (int ni = 0; ni < 4; ++ni)
          acc[0][mi][ni] = __builtin_amdgcn_mfma_f32_16x16x32_bf16(af[ks][mi], bfr[ks][ni], acc[0][mi][ni], 0, 0, 0);
    __builtin_amdgcn_s_setprio(0);
    GBAR();

    // ---- P1: A(t).mh1 x8, 32 MFMA -> acc[1] (B reused in regs) ----
    stageBpair(t + 2);
    DSRO(af[0][0], aA, "4096");   DSRO(af[0][1], aA, "5120");
    DSRO(af[0][2], aA, "6144");   DSRO(af[0][3], aA, "7168");
    DSRO(af[1][0], aA, "20480");  DSRO(af[1][1], aA, "21504");
    DSRO(af[1][2], aA, "22528");  DSRO(af[1][3], aA, "23552");
    GBAR();
    LGKM0();
    __builtin_amdgcn_s_setprio(1);
    #pragma unroll
    for (int ks = 0; ks < 2; ++ks)
      #pragma unroll
      for (int mi = 0; mi < 4; ++mi)
        #pragma unroll
        for (int ni = 0; ni < 4; ++ni)
          acc[1][mi][ni] = __builtin_amdgcn_mfma_f32_16x16x32_bf16(af[ks][mi], bfr[ks][ni], acc[1][mi][ni], 0, 0, 0);
    __builtin_amdgcn_s_setprio(0);
    GWAIT4();         // forces A(t+1), B(t+1) landed for next P0
    GBAR();
  }

  GWAIT0();   // drain clamped tail stages before LDS reassignment

  // epilogue
  const int cm0 = m0 + wm * 128 + quad * 4;
  const int cn0 = n0 + wn * 64 + lrow;
  #pragma unroll
  for (int mh = 0; mh < 2; ++mh)
    #pragma unroll
    for (int mi = 0; mi < 4; ++mi)
      #pragma unroll
      for (int r = 0; r < 4; ++r) {
        const int gm = cm0 + mh * 64 + mi * 16 + r;
        #pragma unroll
        for (int ni = 0; ni < 4; ++ni) {
          const int gn = cn0 + ni * 16;
          float v = acc[mh][mi][ni][r];
          size_t oi = (size_t)gm * N + gn;
          if (MODE == 0) {
            ((__hip_bfloat16*)Out)[oi] = __float2bfloat16(v);
          } else {
            float tt = v + bias[gn];
            float g = 0.5f * tt * (1.0f + erff(tt * 0.70710678118654752f));
            ((__hip_bfloat16*)Out)[oi] = __float2bfloat16(g);
          }
        }
      }
}

// ---------------------------------------------------------------------------
// Pair-balanced MFMA flash attention with XOR-swizzled LDS + reg prefetch.
// ---------------------------------------------------------------------------
__global__ __launch_bounds__(256, 2)
void attn_pair(const __hip_bfloat16* __restrict__ qkv, __hip_bfloat16* __restrict__ o)
{
  const int p = blockIdx.x;            // 0..3
  const int h = blockIdx.y, b = blockIdx.z;
  const int t0 = p, t1 = 7 - p;

  __shared__ __align__(16) __hip_bfloat16 Qs[2][64 * 64];
  __shared__ __align__(16) __hip_bfloat16 Ks[64 * 64];
  __shared__ __align__(16) __hip_bfloat16 Vt[64 * 64];   // (dh, key), swizzled
  __shared__ __align__(16) __hip_bfloat16 Ps[4][16 * 64];

  const int tid = threadIdx.x, lane = tid & 63, wave = tid >> 6;
  const int quad = lane >> 4, col = lane & 15;
  const size_t base = ((size_t)b * Ss) * 1536 + (size_t)h * 64;

  // stage Q for both tiles (swizzled)
  #pragma unroll
  for (int t = 0; t < 2; ++t) {
    const int tq = t ? t1 : t0;
    #pragma unroll
    for (int it = 0; it < 2; ++it) {
      int c = it * 256 + tid;
      int row = c >> 3, seg = c & 7;
      bf16x8 q8 = *reinterpret_cast<const bf16x8*>(
          qkv + base + (size_t)(tq * 64 + row) * 1536 + seg * 8);
      *reinterpret_cast<bf16x8*>(&Qs[t][swz(row, seg)]) = q8;
    }
  }

  bf16x8 kreg[2], vreg[2];
  auto load_kv = [&](int c0) {
    #pragma unroll
    for (int it = 0; it < 2; ++it) {
      int c = it * 256 + tid;
      kreg[it] = *reinterpret_cast<const bf16x8*>(
          qkv + base + 512 + (size_t)(c0 * 64 + (c >> 3)) * 1536 + (c & 7) * 8);
    }
    #pragma unroll
    for (int it = 0; it < 2; ++it) {
      int row = tid & 63, seg = it * 4 + wave;
      vreg[it] = *reinterpret_cast<const bf16x8*>(
          qkv + base + 1024 + (size_t)(c0 * 64 + row) * 1536 + seg * 8);
    }
  };
  auto store_kv = [&]() {
    #pragma unroll
    for (int it = 0; it < 2; ++it) {
      int c = it * 256 + tid;
      *reinterpret_cast<bf16x8*>(&Ks[swz(c >> 3, c & 7)]) = kreg[it];
    }
    #pragma unroll
    for (int it = 0; it < 2; ++it) {
      int row = tid & 63, seg = it * 4 + wave;
      union { bf16x8 v; __hip_bfloat16 e[8]; } u; u.v = vreg[it];
      #pragma unroll
      for (int j = 0; j < 8; ++j) {
        int d = seg * 8 + j;
        Vt[d * 64 + ((((row >> 3)) ^ (d & 7)) << 3) + (row & 7)] = u.e[j];
      }
    }
  };

  float  mrow[2][4], lsum[2][4];
  floatx4 accO[2][4];
  #pragma unroll
  for (int t = 0; t < 2; ++t)
    #pragma unroll
    for (int r = 0; r < 4; ++r) {
      mrow[t][r] = -1e30f; lsum[t][r] = 0.f;
      floatx4 z4 = {0.f, 0.f, 0.f, 0.f};
      accO[t][r] = z4;
    }

  auto compute_tile = [&](const __hip_bfloat16* Qt, int tq, int c,
                          float* mr, float* ls, floatx4* aO) {
    floatx4 accS[4];
    #pragma unroll
    for (int i = 0; i < 4; ++i) { floatx4 z4 = {0.f,0.f,0.f,0.f}; accS[i] = z4; }
    const int m = wave * 16 + col;
    #pragma unroll
    for (int kc = 0; kc < 2; ++kc) {
      bf16x8 aq = *reinterpret_cast<const bf16x8*>(&Qt[swz(m, kc * 4 + quad)]);
      #pragma unroll
      for (int ni = 0; ni < 4; ++ni) {
        bf16x8 bk = *reinterpret_cast<const bf16x8*>(&Ks[swz(ni * 16 + col, kc * 4 + quad)]);
        accS[ni] = __builtin_amdgcn_mfma_f32_16x16x32_bf16(aq, bk, accS[ni], 0, 0, 0);
      }
    }

    const bool diag = (c == tq);
    float sc[4][4];
    #pragma unroll
    for (int ni = 0; ni < 4; ++ni)
      #pragma unroll
      for (int r = 0; r < 4; ++r) {
        float s = accS[ni][r] * 0.125f;
        if (diag && (ni * 16 + col) > (wave * 16 + quad * 4 + r)) s = -1e30f;
        sc[ni][r] = s;
      }

    #pragma unroll
    for (int r = 0; r < 4; ++r) {
      float cm = fmaxf(fmaxf(sc[0][r], sc[1][r]), fmaxf(sc[2][r], sc[3][r]));
      #pragma unroll
      for (int off = 1; off < 16; off <<= 1) cm = fmaxf(cm, __shfl_xor(cm, off));
      float mnew = fmaxf(mr[r], cm);
      float alpha = __expf(mr[r] - mnew);
      mr[r] = mnew;
      float ps = 0.f;
      #pragma unroll
      for (int ni = 0; ni < 4; ++ni) {
        float pv = __expf(sc[ni][r] - mnew);
        sc[ni][r] = pv;
        ps += pv;
      }
      #pragma unroll
      for (int off = 1; off < 16; off <<= 1) ps += __shfl_xor(ps, off);
      ls[r] = ls[r] * alpha + ps;
      #pragma unroll
      for (int ni = 0; ni < 4; ++ni) aO[ni][r] *= alpha;
    }

    #pragma unroll
    for (int ni = 0; ni < 4; ++ni)
      #pragma unroll
      for (int r = 0; r < 4; ++r) {
        int prow = quad * 4 + r;
        int pseg = ni * 2 + (col >> 3);
        Ps[wave][prow * 64 + ((pseg ^ (prow & 7)) << 3) + (col & 7)] =
            __float2bfloat16(sc[ni][r]);
      }

    #pragma unroll
    for (int kc = 0; kc < 2; ++kc) {
      bf16x8 ap = *reinterpret_cast<const bf16x8*>(&Ps[wave][swz(col, kc * 4 + quad)]);
      #pragma unroll
      for (int ni = 0; ni < 4; ++ni) {
        bf16x8 bv = *reinterpret_cast<const bf16x8*>(&Vt[swz(ni * 16 + col, kc * 4 + quad)]);
        aO[ni] = __builtin_amdgcn_mfma_f32_16x16x32_bf16(ap, bv, aO[ni], 0, 0, 0);
      }
    }
  };

  load_kv(0);
  for (int c = 0; c <= t1; ++c) {
    __syncthreads();
    store_kv();
    __syncthreads();
    if (c < t1) load_kv(c + 1);
    compute_tile(Qs[1], t1, c, mrow[1], lsum[1], accO[1]);
    if (c <= t0) compute_tile(Qs[0], t0, c, mrow[0], lsum[0], accO[0]);
  }

  #pragma unroll
  for (int t = 0; t < 2; ++t) {
    const int tq = t ? t1 : t0;
    float inv[4];
    #pragma unroll
    for (int r = 0; r < 4; ++r) inv[r] = 1.f / lsum[t][r];
    #pragma unroll
    for (int ni = 0; ni < 4; ++ni)
      #pragma unroll
      for (int r = 0; r < 4; ++r) {
        int qg = tq * 64 + wave * 16 + quad * 4 + r;
        o[((size_t)b * Ss + qg) * INNERi + h * 64 + ni * 16 + col] =
            __float2bfloat16(accO[t][ni][r] * inv[r]);
      }
  }
}

// ---------------------------------------------------------------------------
// Epilogue gather: out[b,d,sp] = x[b, 255+sp, d]
// ---------------------------------------------------------------------------
__global__ void epilogue_kernel(const float* __restrict__ x, float* __restrict__ out)
{
  int idx = blockIdx.x * 256 + threadIdx.x;    // over B*D*256
  int sp = idx & 255;
  int bd = idx >> 8;
  int b = bd >> 9, d = bd & 511;
  out[idx] = x[((size_t)b * Ss + (NCc - 1) + sp) * Dd + d];
}

// ---------------------------------------------------------------------------
extern "C" void kernel_launch(void* const* d_in, const int* in_sizes, int n_in,
                              void* d_out, int out_size, void* d_ws, size_t ws_size,
                              hipStream_t stream)
{
  const float* z       = (const float*)d_in[0];
  const float* slots   = (const float*)d_in[1];
  const float* pos_emb = (const float*)d_in[2];
  const float* spos    = (const float*)d_in[3];
  const float* norm_w  = (const float*)d_in[4];
  const float* norm_b  = (const float*)d_in[5];
  const float* ln1_w   = (const float*)d_in[6];
  const float* ln1_b   = (const float*)d_in[7];
  const float* qkv_w   = (const float*)d_in[8];
  const float* out_w   = (const float*)d_in[9];
  const float* out_b   = (const float*)d_in[10];
  const float* ln2_w   = (const float*)d_in[11];
  const float* ln2_b   = (const float*)d_in[12];
  const float* mlp_w1  = (const float*)d_in[13];
  const float* mlp_b1  = (const float*)d_in[14];
  const float* mlp_w2  = (const float*)d_in[15];
  const float* mlp_b2  = (const float*)d_in[16];

  char* ws = (char*)d_ws;
  float*          xbuf = (float*)ws;
  __hip_bfloat16* ybuf = (__hip_bfloat16*)(ws + 33554432);
  __hip_bfloat16* qkvb = (__hip_bfloat16*)(ws + 50331648);
  __hip_bfloat16* obuf = (__hip_bfloat16*)(ws + 100663296);
  __hip_bfloat16* hbuf = (__hip_bfloat16*)(ws + 50331648);
  __hip_bfloat16* wT   = (__hip_bfloat16*)(ws + 117440512);

  const size_t WL = 3145728;

  // allow 128 KiB dynamic LDS for the 256^2 GEMMs
  hipFuncSetAttribute(reinterpret_cast<const void*>(&gemm256<0>),
                      hipFuncAttributeMaxDynamicSharedMemorySize, 131072);
  hipFuncSetAttribute(reinterpret_cast<const void*>(&gemm256<2>),
                      hipFuncAttributeMaxDynamicSharedMemorySize, 131072);

  dim3 tb(32, 8);
  transpose_w<<<dim3(1536 / 32, 512 / 32, 8), tb, 0, stream>>>(qkv_w,  wT + 0,       512, 1536, (size_t)512 * 1536, WL);
  transpose_w<<<dim3(512 / 32,  512 / 32, 8), tb, 0, stream>>>(out_w,  wT + 786432,  512, 512,  (size_t)512 * 512,  WL);
  transpose_w<<<dim3(2048 / 32, 512 / 32, 8), tb, 0, stream>>>(mlp_w1, wT + 1048576, 512, 2048, (size_t)512 * 2048, WL);
  transpose_w<<<dim3(512 / 32, 2048 / 32, 8), tb, 0, stream>>>(mlp_w2, wT + 2097152, 2048, 512, (size_t)2048 * 512, WL);

  prologue_kernel<<<Mrows, 64, 0, stream>>>(z, slots, pos_emb, spos, norm_w, norm_b, xbuf);

  for (int i = 0; i < 8; ++i) {
    const __hip_bfloat16* qkvT = wT + (size_t)i * WL;
    const __hip_bfloat16* outT = wT + (size_t)i * WL + 786432;
    const __hip_bfloat16* w1T  = wT + (size_t)i * WL + 1048576;
    const __hip_bfloat16* w2T  = wT + (size_t)i * WL + 2097152;

    ln_kernel<<<Mrows / 4, 256, 0, stream>>>(xbuf, ln1_w + i * Dd, ln1_b + i * Dd, ybuf);
    gemm256<0><<<dim3((1536 / 256) * (Mrows / 256)), 512, 131072, stream>>>(
        ybuf, qkvT, nullptr, qkvb, Mrows, 1536, 512);
    attn_pair<<<dim3(4, NHh, Bb), 256, 0, stream>>>(qkvb, obuf);
    gemm_bt<1><<<dim3((512 / 128) * (Mrows / 128)), 256, 0, stream>>>(
        obuf, outT, out_b + i * Dd, xbuf, xbuf, Mrows, 512, 512);
    ln_kernel<<<Mrows / 4, 256, 0, stream>>>(xbuf, ln2_w + i * Dd, ln2_b + i * Dd, ybuf);
    gemm256<2><<<dim3((2048 / 256) * (Mrows / 256)), 512, 131072, stream>>>(
        ybuf, w1T, mlp_b1 + i * MLPm, hbuf, Mrows, 2048, 512);
    gemm_bt<1><<<dim3((512 / 128) * (Mrows / 128)), 256, 0, stream>>>(
        hbuf, w2T, mlp_b2 + i * Dd, xbuf, xbuf, Mrows, 512, 2048);
  }

  epilogue_kernel<<<(Bb * Dd * 256) / 256, 256, 0, stream>>>(xbuf, (float*)d_out);
}

// Round 4
// 1942.340 us; speedup vs baseline: 1.0872x; 1.0872x over previous
//
#include <hip/hip_runtime.h>
#include <hip/hip_bf16.h>
#include <math.h>

// Problem constants
#define Bb 32
#define Dd 512
#define Ss 512      // NC + Hs*Ws
#define NHh 8
#define DHh 64
#define MLPm 2048
#define NCc 256
#define INNERi 512
#define Mrows (Bb*Ss)   // 16384

typedef __bf16 bf16x8 __attribute__((ext_vector_type(8)));
typedef float floatx4 __attribute__((ext_vector_type(4)));

__device__ __forceinline__ void load_lds16(const void* g, void* l) {
  __builtin_amdgcn_global_load_lds(
      (__attribute__((address_space(1))) void*)(g),
      (__attribute__((address_space(3))) void*)(l), 16, 0, 0);
}

// XOR-swizzled LDS addressing for 64-elem bf16 rows: logical (row, seg8)
// stored at row*64 + ((seg ^ (row&7))<<3). b128 frag reads spread banks.
__device__ __forceinline__ int swz(int row, int seg) {
  return row * 64 + (((seg) ^ (row & 7)) << 3);
}

// Fast gelu: Abramowitz-Stegun 7.1.26 erf (|err| <= 1.5e-7, well below bf16
// output quantization) + __expf. Replaces libm erff (~2-3x cheaper, no branch).
__device__ __forceinline__ float fast_gelu(float t) {
  float ax = fabsf(t) * 0.70710678118654752f;
  float u  = 1.0f / fmaf(0.3275911f, ax, 1.0f);
  float poly = u * fmaf(u, fmaf(u, fmaf(u, fmaf(u, 1.061405429f, -1.453152027f),
                                        1.421413741f), -0.284496736f), 0.254829592f);
  float erfv = 1.0f - poly * __expf(-ax * ax);
  erfv = copysignf(erfv, t);
  return 0.5f * t * (1.0f + erfv);
}

// ---------------------------------------------------------------------------
// Tiled transpose + fp32->bf16 downcast: in (K,N) fp32 -> out (N,K) bf16
// ---------------------------------------------------------------------------
__global__ void transpose_w(const float* __restrict__ in, __hip_bfloat16* __restrict__ out,
                            int K, int N, size_t in_ls, size_t out_ls)
{
  __shared__ float tile[32][33];
  in  += (size_t)blockIdx.z * in_ls;
  out += (size_t)blockIdx.z * out_ls;
  int n0 = blockIdx.x * 32, k0 = blockIdx.y * 32;
  int tx = threadIdx.x;
  #pragma unroll
  for (int i = threadIdx.y; i < 32; i += 8)
    tile[i][tx] = in[(size_t)(k0 + i) * N + n0 + tx];
  __syncthreads();
  #pragma unroll
  for (int i = threadIdx.y; i < 32; i += 8)
    out[(size_t)(n0 + i) * K + k0 + tx] = __float2bfloat16(tile[tx][i]);
}

// ---------------------------------------------------------------------------
// Prologue: build x[b,s,:] (slots+slot_pos | z^T+pos), then LayerNorm(norm_w/b)
// Slot rows (s<NC) take the float4-vectorized path; z rows are a transpose
// read (inherently uncoalesced) and stay scalar.
// ---------------------------------------------------------------------------
__global__ void prologue_kernel(const float* __restrict__ z, const float* __restrict__ slots,
                                const float* __restrict__ pos, const float* __restrict__ spos,
                                const float* __restrict__ nw, const float* __restrict__ nb,
                                float* __restrict__ x)
{
  int row = blockIdx.x;            // b*S + s
  int b = row >> 9, s = row & 511;
  int lane = threadIdx.x;
  float v[8];
  float sum = 0.f;
  if (s < NCc) {
    const float4* s4 = reinterpret_cast<const float4*>(slots + ((size_t)b * NCc + s) * Dd) + lane * 2;
    const float4* p4 = reinterpret_cast<const float4*>(spos + (size_t)s * Dd) + lane * 2;
    float4 a0 = s4[0], a1 = s4[1], q0 = p4[0], q1 = p4[1];
    v[0] = a0.x + q0.x; v[1] = a0.y + q0.y; v[2] = a0.z + q0.z; v[3] = a0.w + q0.w;
    v[4] = a1.x + q1.x; v[5] = a1.y + q1.y; v[6] = a1.z + q1.z; v[7] = a1.w + q1.w;
    #pragma unroll
    for (int j = 0; j < 8; ++j) sum += v[j];
  } else {
    int sp = s - NCc;
    #pragma unroll
    for (int j = 0; j < 8; ++j) {
      int d = lane + j * 64;
      float t = z[((size_t)b * Dd + d) * 256 + sp] + pos[(size_t)sp * Dd + d];
      v[j] = t; sum += t;
    }
  }
  #pragma unroll
  for (int o = 32; o; o >>= 1) sum += __shfl_xor(sum, o);
  float mean = sum * (1.f / Dd);
  float vs = 0.f;
  #pragma unroll
  for (int j = 0; j < 8; ++j) { float d = v[j] - mean; vs += d * d; }
  #pragma unroll
  for (int o = 32; o; o >>= 1) vs += __shfl_xor(vs, o);
  float rs = rsqrtf(vs * (1.f / Dd) + 1e-5f);
  if (s < NCc) {
    const float4* w4 = reinterpret_cast<const float4*>(nw) + lane * 2;
    const float4* b4 = reinterpret_cast<const float4*>(nb) + lane * 2;
    float4 w0 = w4[0], w1 = w4[1], c0 = b4[0], c1 = b4[1];
    float4 o0, o1;
    o0.x = (v[0]-mean)*rs*w0.x + c0.x; o0.y = (v[1]-mean)*rs*w0.y + c0.y;
    o0.z = (v[2]-mean)*rs*w0.z + c0.z; o0.w = (v[3]-mean)*rs*w0.w + c0.w;
    o1.x = (v[4]-mean)*rs*w1.x + c1.x; o1.y = (v[5]-mean)*rs*w1.y + c1.y;
    o1.z = (v[6]-mean)*rs*w1.z + c1.z; o1.w = (v[7]-mean)*rs*w1.w + c1.w;
    float4* xo = reinterpret_cast<float4*>(x + (size_t)row * Dd) + lane * 2;
    xo[0] = o0; xo[1] = o1;
  } else {
    #pragma unroll
    for (int j = 0; j < 8; ++j) {
      int d = lane + j * 64;
      x[(size_t)row * Dd + d] = (v[j] - mean) * rs * nw[d] + nb[d];
    }
  }
}

// ---------------------------------------------------------------------------
// LayerNorm: x fp32 (rows,512) -> y bf16. Vectorized: 2x float4 loads,
// one bf16x8 store per lane (per-lane contiguous chunk; downstream GEMMs
// are index-agnostic).
// ---------------------------------------------------------------------------
__global__ void ln_kernel(const float* __restrict__ x, const float* __restrict__ w,
                          const float* __restrict__ b, __hip_bfloat16* __restrict__ y)
{
  int row = blockIdx.x * 4 + (threadIdx.x >> 6);
  int lane = threadIdx.x & 63;
  const float4* xr = reinterpret_cast<const float4*>(x + (size_t)row * Dd) + lane * 2;
  float4 va = xr[0], vb = xr[1];
  float v[8] = {va.x, va.y, va.z, va.w, vb.x, vb.y, vb.z, vb.w};
  float sum = 0.f;
  #pragma unroll
  for (int j = 0; j < 8; ++j) sum += v[j];
  #pragma unroll
  for (int o = 32; o; o >>= 1) sum += __shfl_xor(sum, o);
  float mean = sum * (1.f / Dd);
  float vs = 0.f;
  #pragma unroll
  for (int j = 0; j < 8; ++j) { float d = v[j] - mean; vs += d * d; }
  #pragma unroll
  for (int o = 32; o; o >>= 1) vs += __shfl_xor(vs, o);
  float rs = rsqrtf(vs * (1.f / Dd) + 1e-5f);
  const float4* w4 = reinterpret_cast<const float4*>(w) + lane * 2;
  const float4* b4 = reinterpret_cast<const float4*>(b) + lane * 2;
  float4 w0 = w4[0], w1 = w4[1], c0 = b4[0], c1 = b4[1];
  float wv[8] = {w0.x, w0.y, w0.z, w0.w, w1.x, w1.y, w1.z, w1.w};
  float bv[8] = {c0.x, c0.y, c0.z, c0.w, c1.x, c1.y, c1.z, c1.w};
  union { bf16x8 v8; __hip_bfloat16 e[8]; } o;
  #pragma unroll
  for (int j = 0; j < 8; ++j)
    o.e[j] = __float2bfloat16((v[j] - mean) * rs * wv[j] + bv[j]);
  *reinterpret_cast<bf16x8*>(y + (size_t)row * Dd + lane * 8) = o.v8;
}

// ---------------------------------------------------------------------------
// bf16 MFMA GEMM: C(M,N) = A(M,K) @ Bt(N,K)^T  [+bias] [+res] [gelu]
// MODE 0: -> bf16 out (no bias);  MODE 1: -> f32 out = acc+bias+res;
// MODE 2: -> bf16 out = gelu(acc+bias)
// 128x128 tile, 2 blocks/CU (m97 structure) — verified best for this
// problem's short K=512 (rounds 1-3: the 256^2 8-phase port is latency-
// bound at 1 block/CU with NT=8; kill criterion fired).
// ---------------------------------------------------------------------------
template <int MODE>
__global__ __launch_bounds__(256, 2)
void gemm_bt(const __hip_bfloat16* __restrict__ A, const __hip_bfloat16* __restrict__ Bt,
             const float* __restrict__ bias, const float* __restrict__ res,
             void* __restrict__ Out, int M, int N, int K)
{
  constexpr int BM = 128, BN = 128, BK = 64;
  __shared__ __align__(16) __hip_bfloat16 As[BM * BK];
  __shared__ __align__(16) __hip_bfloat16 Bs[BN * BK];
  const int tid = threadIdx.x;
  const int lane = tid & 63;
  const int wave = tid >> 6;

  // XCD-aware block swizzle (bid%8 -> XCD heuristic; neutral if mapping differs)
  const int NBLK = N >> 7;
  const int bid = blockIdx.x;
  const int xcd = bid & 7;
  const int j = bid >> 3;
  const int nb = j % NBLK;
  const int mt = xcd + ((j / NBLK) << 3);
  const int m0 = mt << 7;
  const int n0 = nb << 7;

  const int wm = (wave & 1) * 64;
  const int wn = (wave >> 1) * 64;
  const int quad = lane >> 4;
  const int lrow = lane & 15;

  floatx4 acc[4][4];
  #pragma unroll
  for (int i = 0; i < 4; ++i)
    #pragma unroll
    for (int jj = 0; jj < 4; ++jj) {
      floatx4 z4 = {0.f, 0.f, 0.f, 0.f};
      acc[i][jj] = z4;
    }

  for (int k0 = 0; k0 < K; k0 += BK) {
    // stage tiles via glds; LDS chunk c is lane-linear (DMA constraint), the
    // GLOBAL segment is XOR-permuted so the LDS layout lands swizzled.
    #pragma unroll
    for (int it = 0; it < 4; ++it) {
      int c = it * 256 + tid;
      int row = c >> 3, seg = (c & 7) ^ (row & 7);
      load_lds16(A + (size_t)(m0 + row) * K + k0 + seg * 8, As + c * 8);
    }
    #pragma unroll
    for (int it = 0; it < 4; ++it) {
      int c = it * 256 + tid;
      int row = c >> 3, seg = (c & 7) ^ (row & 7);
      load_lds16(Bt + (size_t)(n0 + row) * K + k0 + seg * 8, Bs + c * 8);
    }
    __syncthreads();

    #pragma unroll
    for (int k1 = 0; k1 < BK; k1 += 32) {
      const int s0 = k1 >> 3;   // 0 or 4
      bf16x8 a[4], b[4];
      #pragma unroll
      for (int i = 0; i < 4; ++i)
        a[i] = *reinterpret_cast<const bf16x8*>(&As[swz(wm + i * 16 + lrow, s0 + quad)]);
      #pragma unroll
      for (int i = 0; i < 4; ++i)
        b[i] = *reinterpret_cast<const bf16x8*>(&Bs[swz(wn + i * 16 + lrow, s0 + quad)]);
      #pragma unroll
      for (int mi = 0; mi < 4; ++mi)
        #pragma unroll
        for (int ni = 0; ni < 4; ++ni)
          acc[mi][ni] = __builtin_amdgcn_mfma_f32_16x16x32_bf16(a[mi], b[ni], acc[mi][ni], 0, 0, 0);
    }
    __syncthreads();
  }

  #pragma unroll
  for (int mi = 0; mi < 4; ++mi) {
    #pragma unroll
    for (int r = 0; r < 4; ++r) {
      int gm = m0 + wm + mi * 16 + quad * 4 + r;
      #pragma unroll
      for (int ni = 0; ni < 4; ++ni) {
        int gn = n0 + wn + ni * 16 + lrow;
        float v = acc[mi][ni][r];
        size_t oi = (size_t)gm * N + gn;
        if (MODE == 0) {
          ((__hip_bfloat16*)Out)[oi] = __float2bfloat16(v);
        } else if (MODE == 1) {
          ((float*)Out)[oi] = v + bias[gn] + res[oi];
        } else {
          ((__hip_bfloat16*)Out)[oi] = __float2bfloat16(fast_gelu(v + bias[gn]));
        }
      }
    }
  }
}

// ---------------------------------------------------------------------------
// Pair-balanced MFMA flash attention with XOR-swizzled LDS + reg prefetch.
// ---------------------------------------------------------------------------
__global__ __launch_bounds__(256, 2)
void attn_pair(const __hip_bfloat16* __restrict__ qkv, __hip_bfloat16* __restrict__ o)
{
  const int p = blockIdx.x;            // 0..3
  const int h = blockIdx.y, b = blockIdx.z;
  const int t0 = p, t1 = 7 - p;

  __shared__ __align__(16) __hip_bfloat16 Qs[2][64 * 64];
  __shared__ __align__(16) __hip_bfloat16 Ks[64 * 64];
  __shared__ __align__(16) __hip_bfloat16 Vt[64 * 64];   // (dh, key), swizzled
  __shared__ __align__(16) __hip_bfloat16 Ps[4][16 * 64];

  const int tid = threadIdx.x, lane = tid & 63, wave = tid >> 6;
  const int quad = lane >> 4, col = lane & 15;
  const size_t base = ((size_t)b * Ss) * 1536 + (size_t)h * 64;

  // stage Q for both tiles (swizzled)
  #pragma unroll
  for (int t = 0; t < 2; ++t) {
    const int tq = t ? t1 : t0;
    #pragma unroll
    for (int it = 0; it < 2; ++it) {
      int c = it * 256 + tid;
      int row = c >> 3, seg = c & 7;
      bf16x8 q8 = *reinterpret_cast<const bf16x8*>(
          qkv + base + (size_t)(tq * 64 + row) * 1536 + seg * 8);
      *reinterpret_cast<bf16x8*>(&Qs[t][swz(row, seg)]) = q8;
    }
  }

  bf16x8 kreg[2], vreg[2];
  auto load_kv = [&](int c0) {
    #pragma unroll
    for (int it = 0; it < 2; ++it) {
      int c = it * 256 + tid;
      kreg[it] = *reinterpret_cast<const bf16x8*>(
          qkv + base + 512 + (size_t)(c0 * 64 + (c >> 3)) * 1536 + (c & 7) * 8);
    }
    #pragma unroll
    for (int it = 0; it < 2; ++it) {
      int row = tid & 63, seg = it * 4 + wave;
      vreg[it] = *reinterpret_cast<const bf16x8*>(
          qkv + base + 1024 + (size_t)(c0 * 64 + row) * 1536 + seg * 8);
    }
  };
  auto store_kv = [&]() {
    #pragma unroll
    for (int it = 0; it < 2; ++it) {
      int c = it * 256 + tid;
      *reinterpret_cast<bf16x8*>(&Ks[swz(c >> 3, c & 7)]) = kreg[it];
    }
    #pragma unroll
    for (int it = 0; it < 2; ++it) {
      int row = tid & 63, seg = it * 4 + wave;
      union { bf16x8 v; __hip_bfloat16 e[8]; } u; u.v = vreg[it];
      #pragma unroll
      for (int j = 0; j < 8; ++j) {
        int d = seg * 8 + j;
        Vt[d * 64 + ((((row >> 3)) ^ (d & 7)) << 3) + (row & 7)] = u.e[j];
      }
    }
  };

  float  mrow[2][4], lsum[2][4];
  floatx4 accO[2][4];
  #pragma unroll
  for (int t = 0; t < 2; ++t)
    #pragma unroll
    for (int r = 0; r < 4; ++r) {
      mrow[t][r] = -1e30f; lsum[t][r] = 0.f;
      floatx4 z4 = {0.f, 0.f, 0.f, 0.f};
      accO[t][r] = z4;
    }

  auto compute_tile = [&](const __hip_bfloat16* Qt, int tq, int c,
                          float* mr, float* ls, floatx4* aO) {
    floatx4 accS[4];
    #pragma unroll
    for (int i = 0; i < 4; ++i) { floatx4 z4 = {0.f,0.f,0.f,0.f}; accS[i] = z4; }
    const int m = wave * 16 + col;
    #pragma unroll
    for (int kc = 0; kc < 2; ++kc) {
      bf16x8 aq = *reinterpret_cast<const bf16x8*>(&Qt[swz(m, kc * 4 + quad)]);
      #pragma unroll
      for (int ni = 0; ni < 4; ++ni) {
        bf16x8 bk = *reinterpret_cast<const bf16x8*>(&Ks[swz(ni * 16 + col, kc * 4 + quad)]);
        accS[ni] = __builtin_amdgcn_mfma_f32_16x16x32_bf16(aq, bk, accS[ni], 0, 0, 0);
      }
    }

    const bool diag = (c == tq);
    float sc[4][4];
    #pragma unroll
    for (int ni = 0; ni < 4; ++ni)
      #pragma unroll
      for (int r = 0; r < 4; ++r) {
        float s = accS[ni][r] * 0.125f;
        if (diag && (ni * 16 + col) > (wave * 16 + quad * 4 + r)) s = -1e30f;
        sc[ni][r] = s;
      }

    #pragma unroll
    for (int r = 0; r < 4; ++r) {
      float cm = fmaxf(fmaxf(sc[0][r], sc[1][r]), fmaxf(sc[2][r], sc[3][r]));
      #pragma unroll
      for (int off = 1; off < 16; off <<= 1) cm = fmaxf(cm, __shfl_xor(cm, off));
      float mnew = fmaxf(mr[r], cm);
      float alpha = __expf(mr[r] - mnew);
      mr[r] = mnew;
      float ps = 0.f;
      #pragma unroll
      for (int ni = 0; ni < 4; ++ni) {
        float pv = __expf(sc[ni][r] - mnew);
        sc[ni][r] = pv;
        ps += pv;
      }
      #pragma unroll
      for (int off = 1; off < 16; off <<= 1) ps += __shfl_xor(ps, off);
      ls[r] = ls[r] * alpha + ps;
      #pragma unroll
      for (int ni = 0; ni < 4; ++ni) aO[ni][r] *= alpha;
    }

    #pragma unroll
    for (int ni = 0; ni < 4; ++ni)
      #pragma unroll
      for (int r = 0; r < 4; ++r) {
        int prow = quad * 4 + r;
        int pseg = ni * 2 + (col >> 3);
        Ps[wave][prow * 64 + ((pseg ^ (prow & 7)) << 3) + (col & 7)] =
            __float2bfloat16(sc[ni][r]);
      }

    #pragma unroll
    for (int kc = 0; kc < 2; ++kc) {
      bf16x8 ap = *reinterpret_cast<const bf16x8*>(&Ps[wave][swz(col, kc * 4 + quad)]);
      #pragma unroll
      for (int ni = 0; ni < 4; ++ni) {
        bf16x8 bv = *reinterpret_cast<const bf16x8*>(&Vt[swz(ni * 16 + col, kc * 4 + quad)]);
        aO[ni] = __builtin_amdgcn_mfma_f32_16x16x32_bf16(ap, bv, aO[ni], 0, 0, 0);
      }
    }
  };

  load_kv(0);
  for (int c = 0; c <= t1; ++c) {
    __syncthreads();
    store_kv();
    __syncthreads();
    if (c < t1) load_kv(c + 1);
    compute_tile(Qs[1], t1, c, mrow[1], lsum[1], accO[1]);
    if (c <= t0) compute_tile(Qs[0], t0, c, mrow[0], lsum[0], accO[0]);
  }

  #pragma unroll
  for (int t = 0; t < 2; ++t) {
    const int tq = t ? t1 : t0;
    float inv[4];
    #pragma unroll
    for (int r = 0; r < 4; ++r) inv[r] = 1.f / lsum[t][r];
    #pragma unroll
    for (int ni = 0; ni < 4; ++ni)
      #pragma unroll
      for (int r = 0; r < 4; ++r) {
        int qg = tq * 64 + wave * 16 + quad * 4 + r;
        o[((size_t)b * Ss + qg) * INNERi + h * 64 + ni * 16 + col] =
            __float2bfloat16(accO[t][ni][r] * inv[r]);
      }
  }
}

// ---------------------------------------------------------------------------
// Epilogue: out[b,d,sp] = x[b, 255+sp, d] — LDS-tiled transpose so both the
// x read (coalesced in d) and the out write (coalesced in sp) are vectorized.
// grid: (256/32, 512/32, B), block (32,8).
// ---------------------------------------------------------------------------
__global__ void epilogue_kernel(const float* __restrict__ x, float* __restrict__ out)
{
  __shared__ float tile[32][33];
  int sp0 = blockIdx.x * 32, d0 = blockIdx.y * 32, b = blockIdx.z;
  int tx = threadIdx.x;
  #pragma unroll
  for (int i = threadIdx.y; i < 32; i += 8)
    tile[i][tx] = x[((size_t)b * Ss + (NCc - 1) + sp0 + i) * Dd + d0 + tx];
  __syncthreads();
  #pragma unroll
  for (int i = threadIdx.y; i < 32; i += 8)
    out[((size_t)b * Dd + d0 + i) * 256 + sp0 + tx] = tile[tx][i];
}

// ---------------------------------------------------------------------------
extern "C" void kernel_launch(void* const* d_in, const int* in_sizes, int n_in,
                              void* d_out, int out_size, void* d_ws, size_t ws_size,
                              hipStream_t stream)
{
  const float* z       = (const float*)d_in[0];
  const float* slots   = (const float*)d_in[1];
  const float* pos_emb = (const float*)d_in[2];
  const float* spos    = (const float*)d_in[3];
  const float* norm_w  = (const float*)d_in[4];
  const float* norm_b  = (const float*)d_in[5];
  const float* ln1_w   = (const float*)d_in[6];
  const float* ln1_b   = (const float*)d_in[7];
  const float* qkv_w   = (const float*)d_in[8];
  const float* out_w   = (const float*)d_in[9];
  const float* out_b   = (const float*)d_in[10];
  const float* ln2_w   = (const float*)d_in[11];
  const float* ln2_b   = (const float*)d_in[12];
  const float* mlp_w1  = (const float*)d_in[13];
  const float* mlp_b1  = (const float*)d_in[14];
  const float* mlp_w2  = (const float*)d_in[15];
  const float* mlp_b2  = (const float*)d_in[16];

  char* ws = (char*)d_ws;
  float*          xbuf = (float*)ws;
  __hip_bfloat16* ybuf = (__hip_bfloat16*)(ws + 33554432);
  __hip_bfloat16* qkvb = (__hip_bfloat16*)(ws + 50331648);
  __hip_bfloat16* obuf = (__hip_bfloat16*)(ws + 100663296);
  __hip_bfloat16* hbuf = (__hip_bfloat16*)(ws + 50331648);
  __hip_bfloat16* wT   = (__hip_bfloat16*)(ws + 117440512);

  const size_t WL = 3145728;

  dim3 tb(32, 8);
  transpose_w<<<dim3(1536 / 32, 512 / 32, 8), tb, 0, stream>>>(qkv_w,  wT + 0,       512, 1536, (size_t)512 * 1536, WL);
  transpose_w<<<dim3(512 / 32,  512 / 32, 8), tb, 0, stream>>>(out_w,  wT + 786432,  512, 512,  (size_t)512 * 512,  WL);
  transpose_w<<<dim3(2048 / 32, 512 / 32, 8), tb, 0, stream>>>(mlp_w1, wT + 1048576, 512, 2048, (size_t)512 * 2048, WL);
  transpose_w<<<dim3(512 / 32, 2048 / 32, 8), tb, 0, stream>>>(mlp_w2, wT + 2097152, 2048, 512, (size_t)2048 * 512, WL);

  prologue_kernel<<<Mrows, 64, 0, stream>>>(z, slots, pos_emb, spos, norm_w, norm_b, xbuf);

  for (int i = 0; i < 8; ++i) {
    const __hip_bfloat16* qkvT = wT + (size_t)i * WL;
    const __hip_bfloat16* outT = wT + (size_t)i * WL + 786432;
    const __hip_bfloat16* w1T  = wT + (size_t)i * WL + 1048576;
    const __hip_bfloat16* w2T  = wT + (size_t)i * WL + 2097152;

    ln_kernel<<<Mrows / 4, 256, 0, stream>>>(xbuf, ln1_w + i * Dd, ln1_b + i * Dd, ybuf);
    gemm_bt<0><<<dim3((1536 / 128) * (Mrows / 128)), 256, 0, stream>>>(
        ybuf, qkvT, nullptr, nullptr, qkvb, Mrows, 1536, 512);
    attn_pair<<<dim3(4, NHh, Bb), 256, 0, stream>>>(qkvb, obuf);
    gemm_bt<1><<<dim3((512 / 128) * (Mrows / 128)), 256, 0, stream>>>(
        obuf, outT, out_b + i * Dd, xbuf, xbuf, Mrows, 512, 512);
    ln_kernel<<<Mrows / 4, 256, 0, stream>>>(xbuf, ln2_w + i * Dd, ln2_b + i * Dd, ybuf);
    gemm_bt<2><<<dim3((2048 / 128) * (Mrows / 128)), 256, 0, stream>>>(
        ybuf, w1T, mlp_b1 + i * MLPm, nullptr, hbuf, Mrows, 2048, 512);
    gemm_bt<1><<<dim3((512 / 128) * (Mrows / 128)), 256, 0, stream>>>(
        hbuf, w2T, mlp_b2 + i * Dd, xbuf, xbuf, Mrows, 512, 2048);
  }

  epilogue_kernel<<<dim3(256 / 32, 512 / 32, Bb), tb, 0, stream>>>(xbuf, (float*)d_out);
}

// Round 5
// 1925.276 us; speedup vs baseline: 1.0968x; 1.0089x over previous
//
#include <hip/hip_runtime.h>
#include <hip/hip_bf16.h>
#include <math.h>

// Problem constants
#define Bb 32
#define Dd 512
#define Ss 512      // NC + Hs*Ws
#define NHh 8
#define DHh 64
#define MLPm 2048
#define NCc 256
#define INNERi 512
#define Mrows (Bb*Ss)   // 16384

typedef __bf16 bf16x8 __attribute__((ext_vector_type(8)));
typedef float floatx4 __attribute__((ext_vector_type(4)));

__device__ __forceinline__ void load_lds16(const void* g, void* l) {
  __builtin_amdgcn_global_load_lds(
      (__attribute__((address_space(1))) void*)(g),
      (__attribute__((address_space(3))) void*)(l), 16, 0, 0);
}

// XOR-swizzled LDS addressing for 64-elem bf16 rows: logical (row, seg8)
// stored at row*64 + ((seg ^ (row&7))<<3). b128 frag reads spread banks.
__device__ __forceinline__ int swz(int row, int seg) {
  return row * 64 + (((seg) ^ (row & 7)) << 3);
}

// Fast gelu: Abramowitz-Stegun 7.1.26 erf (|err| <= 1.5e-7, well below bf16
// output quantization) + __expf.
__device__ __forceinline__ float fast_gelu(float t) {
  float ax = fabsf(t) * 0.70710678118654752f;
  float u  = 1.0f / fmaf(0.3275911f, ax, 1.0f);
  float poly = u * fmaf(u, fmaf(u, fmaf(u, fmaf(u, 1.061405429f, -1.453152027f),
                                        1.421413741f), -0.284496736f), 0.254829592f);
  float erfv = 1.0f - poly * __expf(-ax * ax);
  erfv = copysignf(erfv, t);
  return 0.5f * t * (1.0f + erfv);
}

// ---------------------------------------------------------------------------
// Tiled transpose + fp32->bf16 downcast: in (K,N) fp32 -> out (N,K) bf16
// ---------------------------------------------------------------------------
__global__ void transpose_w(const float* __restrict__ in, __hip_bfloat16* __restrict__ out,
                            int K, int N, size_t in_ls, size_t out_ls)
{
  __shared__ float tile[32][33];
  in  += (size_t)blockIdx.z * in_ls;
  out += (size_t)blockIdx.z * out_ls;
  int n0 = blockIdx.x * 32, k0 = blockIdx.y * 32;
  int tx = threadIdx.x;
  #pragma unroll
  for (int i = threadIdx.y; i < 32; i += 8)
    tile[i][tx] = in[(size_t)(k0 + i) * N + n0 + tx];
  __syncthreads();
  #pragma unroll
  for (int i = threadIdx.y; i < 32; i += 8)
    out[(size_t)(n0 + i) * K + k0 + tx] = __float2bfloat16(tile[tx][i]);
}

// ---------------------------------------------------------------------------
// Prologue: build x[b,s,:] (slots+slot_pos | z^T+pos), then LayerNorm(norm_w/b)
// ---------------------------------------------------------------------------
__global__ void prologue_kernel(const float* __restrict__ z, const float* __restrict__ slots,
                                const float* __restrict__ pos, const float* __restrict__ spos,
                                const float* __restrict__ nw, const float* __restrict__ nb,
                                float* __restrict__ x)
{
  int row = blockIdx.x;            // b*S + s
  int b = row >> 9, s = row & 511;
  int lane = threadIdx.x;
  float v[8];
  float sum = 0.f;
  if (s < NCc) {
    const float4* s4 = reinterpret_cast<const float4*>(slots + ((size_t)b * NCc + s) * Dd) + lane * 2;
    const float4* p4 = reinterpret_cast<const float4*>(spos + (size_t)s * Dd) + lane * 2;
    float4 a0 = s4[0], a1 = s4[1], q0 = p4[0], q1 = p4[1];
    v[0] = a0.x + q0.x; v[1] = a0.y + q0.y; v[2] = a0.z + q0.z; v[3] = a0.w + q0.w;
    v[4] = a1.x + q1.x; v[5] = a1.y + q1.y; v[6] = a1.z + q1.z; v[7] = a1.w + q1.w;
    #pragma unroll
    for (int j = 0; j < 8; ++j) sum += v[j];
  } else {
    int sp = s - NCc;
    #pragma unroll
    for (int j = 0; j < 8; ++j) {
      int d = lane + j * 64;
      float t = z[((size_t)b * Dd + d) * 256 + sp] + pos[(size_t)sp * Dd + d];
      v[j] = t; sum += t;
    }
  }
  #pragma unroll
  for (int o = 32; o; o >>= 1) sum += __shfl_xor(sum, o);
  float mean = sum * (1.f / Dd);
  float vs = 0.f;
  #pragma unroll
  for (int j = 0; j < 8; ++j) { float d = v[j] - mean; vs += d * d; }
  #pragma unroll
  for (int o = 32; o; o >>= 1) vs += __shfl_xor(vs, o);
  float rs = rsqrtf(vs * (1.f / Dd) + 1e-5f);
  if (s < NCc) {
    const float4* w4 = reinterpret_cast<const float4*>(nw) + lane * 2;
    const float4* b4 = reinterpret_cast<const float4*>(nb) + lane * 2;
    float4 w0 = w4[0], w1 = w4[1], c0 = b4[0], c1 = b4[1];
    float4 o0, o1;
    o0.x = (v[0]-mean)*rs*w0.x + c0.x; o0.y = (v[1]-mean)*rs*w0.y + c0.y;
    o0.z = (v[2]-mean)*rs*w0.z + c0.z; o0.w = (v[3]-mean)*rs*w0.w + c0.w;
    o1.x = (v[4]-mean)*rs*w1.x + c1.x; o1.y = (v[5]-mean)*rs*w1.y + c1.y;
    o1.z = (v[6]-mean)*rs*w1.z + c1.z; o1.w = (v[7]-mean)*rs*w1.w + c1.w;
    float4* xo = reinterpret_cast<float4*>(x + (size_t)row * Dd) + lane * 2;
    xo[0] = o0; xo[1] = o1;
  } else {
    #pragma unroll
    for (int j = 0; j < 8; ++j) {
      int d = lane + j * 64;
      x[(size_t)row * Dd + d] = (v[j] - mean) * rs * nw[d] + nb[d];
    }
  }
}

// ---------------------------------------------------------------------------
// LayerNorm: x fp32 (rows,512) -> y bf16. Vectorized.
// ---------------------------------------------------------------------------
__global__ void ln_kernel(const float* __restrict__ x, const float* __restrict__ w,
                          const float* __restrict__ b, __hip_bfloat16* __restrict__ y)
{
  int row = blockIdx.x * 4 + (threadIdx.x >> 6);
  int lane = threadIdx.x & 63;
  const float4* xr = reinterpret_cast<const float4*>(x + (size_t)row * Dd) + lane * 2;
  float4 va = xr[0], vb = xr[1];
  float v[8] = {va.x, va.y, va.z, va.w, vb.x, vb.y, vb.z, vb.w};
  float sum = 0.f;
  #pragma unroll
  for (int j = 0; j < 8; ++j) sum += v[j];
  #pragma unroll
  for (int o = 32; o; o >>= 1) sum += __shfl_xor(sum, o);
  float mean = sum * (1.f / Dd);
  float vs = 0.f;
  #pragma unroll
  for (int j = 0; j < 8; ++j) { float d = v[j] - mean; vs += d * d; }
  #pragma unroll
  for (int o = 32; o; o >>= 1) vs += __shfl_xor(vs, o);
  float rs = rsqrtf(vs * (1.f / Dd) + 1e-5f);
  const float4* w4 = reinterpret_cast<const float4*>(w) + lane * 2;
  const float4* b4 = reinterpret_cast<const float4*>(b) + lane * 2;
  float4 w0 = w4[0], w1 = w4[1], c0 = b4[0], c1 = b4[1];
  float wv[8] = {w0.x, w0.y, w0.z, w0.w, w1.x, w1.y, w1.z, w1.w};
  float bv[8] = {c0.x, c0.y, c0.z, c0.w, c1.x, c1.y, c1.z, c1.w};
  union { bf16x8 v8; __hip_bfloat16 e[8]; } o;
  #pragma unroll
  for (int j = 0; j < 8; ++j)
    o.e[j] = __float2bfloat16((v[j] - mean) * rs * wv[j] + bv[j]);
  *reinterpret_cast<bf16x8*>(y + (size_t)row * Dd + lane * 8) = o.v8;
}

// ---------------------------------------------------------------------------
// bf16 MFMA GEMM: C(M,N) = A(M,K) @ Bt(N,K)^T  [+bias] [+res] [gelu]
// MODE 0: -> bf16 out (no bias);  MODE 1: -> f32 out = acc+bias+res;
// MODE 2: -> bf16 out = gelu(acc+bias)
//
// ROUND 5: __launch_bounds__(256, 4) — resource audit showed 4 blocks/CU fit
// (VGPR 60 + AGPR 64 = 124 <= 128/thread tier; LDS 4x32KB = 128 <= 160KB)
// but the old (256,2) annotation capped residency at 2. The m97 structure's
// per-K-iter vmcnt(0)+barrier drain is hidden by co-resident blocks (m114);
// doubling co-residency attacks exactly the latency-bound signature
// (MfmaUtil 24 / VALU 60 / HBM 20 / Occ 32 — nothing saturated).
// ---------------------------------------------------------------------------
template <int MODE>
__global__ __launch_bounds__(256, 4)
void gemm_bt(const __hip_bfloat16* __restrict__ A, const __hip_bfloat16* __restrict__ Bt,
             const float* __restrict__ bias, const float* __restrict__ res,
             void* __restrict__ Out, int M, int N, int K)
{
  constexpr int BM = 128, BN = 128, BK = 64;
  __shared__ __align__(16) __hip_bfloat16 As[BM * BK];
  __shared__ __align__(16) __hip_bfloat16 Bs[BN * BK];
  const int tid = threadIdx.x;
  const int lane = tid & 63;
  const int wave = tid >> 6;

  // XCD-aware block swizzle (bid%8 -> XCD heuristic; neutral if mapping differs)
  const int NBLK = N >> 7;
  const int bid = blockIdx.x;
  const int xcd = bid & 7;
  const int j = bid >> 3;
  const int nb = j % NBLK;
  const int mt = xcd + ((j / NBLK) << 3);
  const int m0 = mt << 7;
  const int n0 = nb << 7;

  const int wm = (wave & 1) * 64;
  const int wn = (wave >> 1) * 64;
  const int quad = lane >> 4;
  const int lrow = lane & 15;

  floatx4 acc[4][4];
  #pragma unroll
  for (int i = 0; i < 4; ++i)
    #pragma unroll
    for (int jj = 0; jj < 4; ++jj) {
      floatx4 z4 = {0.f, 0.f, 0.f, 0.f};
      acc[i][jj] = z4;
    }

  for (int k0 = 0; k0 < K; k0 += BK) {
    // stage tiles via glds; LDS chunk c is lane-linear (DMA constraint), the
    // GLOBAL segment is XOR-permuted so the LDS layout lands swizzled.
    #pragma unroll
    for (int it = 0; it < 4; ++it) {
      int c = it * 256 + tid;
      int row = c >> 3, seg = (c & 7) ^ (row & 7);
      load_lds16(A + (size_t)(m0 + row) * K + k0 + seg * 8, As + c * 8);
    }
    #pragma unroll
    for (int it = 0; it < 4; ++it) {
      int c = it * 256 + tid;
      int row = c >> 3, seg = (c & 7) ^ (row & 7);
      load_lds16(Bt + (size_t)(n0 + row) * K + k0 + seg * 8, Bs + c * 8);
    }
    __syncthreads();

    #pragma unroll
    for (int k1 = 0; k1 < BK; k1 += 32) {
      const int s0 = k1 >> 3;   // 0 or 4
      bf16x8 a[4], b[4];
      #pragma unroll
      for (int i = 0; i < 4; ++i)
        a[i] = *reinterpret_cast<const bf16x8*>(&As[swz(wm + i * 16 + lrow, s0 + quad)]);
      #pragma unroll
      for (int i = 0; i < 4; ++i)
        b[i] = *reinterpret_cast<const bf16x8*>(&Bs[swz(wn + i * 16 + lrow, s0 + quad)]);
      #pragma unroll
      for (int mi = 0; mi < 4; ++mi)
        #pragma unroll
        for (int ni = 0; ni < 4; ++ni)
          acc[mi][ni] = __builtin_amdgcn_mfma_f32_16x16x32_bf16(a[mi], b[ni], acc[mi][ni], 0, 0, 0);
    }
    __syncthreads();
  }

  #pragma unroll
  for (int mi = 0; mi < 4; ++mi) {
    #pragma unroll
    for (int r = 0; r < 4; ++r) {
      int gm = m0 + wm + mi * 16 + quad * 4 + r;
      #pragma unroll
      for (int ni = 0; ni < 4; ++ni) {
        int gn = n0 + wn + ni * 16 + lrow;
        float v = acc[mi][ni][r];
        size_t oi = (size_t)gm * N + gn;
        if (MODE == 0) {
          ((__hip_bfloat16*)Out)[oi] = __float2bfloat16(v);
        } else if (MODE == 1) {
          ((float*)Out)[oi] = v + bias[gn] + res[oi];
        } else {
          ((__hip_bfloat16*)Out)[oi] = __float2bfloat16(fast_gelu(v + bias[gn]));
        }
      }
    }
  }
}

// ---------------------------------------------------------------------------
// Pair-balanced MFMA flash attention with XOR-swizzled LDS + reg prefetch.
// ---------------------------------------------------------------------------
__global__ __launch_bounds__(256, 2)
void attn_pair(const __hip_bfloat16* __restrict__ qkv, __hip_bfloat16* __restrict__ o)
{
  const int p = blockIdx.x;            // 0..3
  const int h = blockIdx.y, b = blockIdx.z;
  const int t0 = p, t1 = 7 - p;

  __shared__ __align__(16) __hip_bfloat16 Qs[2][64 * 64];
  __shared__ __align__(16) __hip_bfloat16 Ks[64 * 64];
  __shared__ __align__(16) __hip_bfloat16 Vt[64 * 64];   // (dh, key), swizzled
  __shared__ __align__(16) __hip_bfloat16 Ps[4][16 * 64];

  const int tid = threadIdx.x, lane = tid & 63, wave = tid >> 6;
  const int quad = lane >> 4, col = lane & 15;
  const size_t base = ((size_t)b * Ss) * 1536 + (size_t)h * 64;

  // stage Q for both tiles (swizzled)
  #pragma unroll
  for (int t = 0; t < 2; ++t) {
    const int tq = t ? t1 : t0;
    #pragma unroll
    for (int it = 0; it < 2; ++it) {
      int c = it * 256 + tid;
      int row = c >> 3, seg = c & 7;
      bf16x8 q8 = *reinterpret_cast<const bf16x8*>(
          qkv + base + (size_t)(tq * 64 + row) * 1536 + seg * 8);
      *reinterpret_cast<bf16x8*>(&Qs[t][swz(row, seg)]) = q8;
    }
  }

  bf16x8 kreg[2], vreg[2];
  auto load_kv = [&](int c0) {
    #pragma unroll
    for (int it = 0; it < 2; ++it) {
      int c = it * 256 + tid;
      kreg[it] = *reinterpret_cast<const bf16x8*>(
          qkv + base + 512 + (size_t)(c0 * 64 + (c >> 3)) * 1536 + (c & 7) * 8);
    }
    #pragma unroll
    for (int it = 0; it < 2; ++it) {
      int row = tid & 63, seg = it * 4 + wave;
      vreg[it] = *reinterpret_cast<const bf16x8*>(
          qkv + base + 1024 + (size_t)(c0 * 64 + row) * 1536 + seg * 8);
    }
  };
  auto store_kv = [&]() {
    #pragma unroll
    for (int it = 0; it < 2; ++it) {
      int c = it * 256 + tid;
      *reinterpret_cast<bf16x8*>(&Ks[swz(c >> 3, c & 7)]) = kreg[it];
    }
    #pragma unroll
    for (int it = 0; it < 2; ++it) {
      int row = tid & 63, seg = it * 4 + wave;
      union { bf16x8 v; __hip_bfloat16 e[8]; } u; u.v = vreg[it];
      #pragma unroll
      for (int j = 0; j < 8; ++j) {
        int d = seg * 8 + j;
        Vt[d * 64 + ((((row >> 3)) ^ (d & 7)) << 3) + (row & 7)] = u.e[j];
      }
    }
  };

  float  mrow[2][4], lsum[2][4];
  floatx4 accO[2][4];
  #pragma unroll
  for (int t = 0; t < 2; ++t)
    #pragma unroll
    for (int r = 0; r < 4; ++r) {
      mrow[t][r] = -1e30f; lsum[t][r] = 0.f;
      floatx4 z4 = {0.f, 0.f, 0.f, 0.f};
      accO[t][r] = z4;
    }

  auto compute_tile = [&](const __hip_bfloat16* Qt, int tq, int c,
                          float* mr, float* ls, floatx4* aO) {
    floatx4 accS[4];
    #pragma unroll
    for (int i = 0; i < 4; ++i) { floatx4 z4 = {0.f,0.f,0.f,0.f}; accS[i] = z4; }
    const int m = wave * 16 + col;
    #pragma unroll
    for (int kc = 0; kc < 2; ++kc) {
      bf16x8 aq = *reinterpret_cast<const bf16x8*>(&Qt[swz(m, kc * 4 + quad)]);
      #pragma unroll
      for (int ni = 0; ni < 4; ++ni) {
        bf16x8 bk = *reinterpret_cast<const bf16x8*>(&Ks[swz(ni * 16 + col, kc * 4 + quad)]);
        accS[ni] = __builtin_amdgcn_mfma_f32_16x16x32_bf16(aq, bk, accS[ni], 0, 0, 0);
      }
    }

    const bool diag = (c == tq);
    float sc[4][4];
    #pragma unroll
    for (int ni = 0; ni < 4; ++ni)
      #pragma unroll
      for (int r = 0; r < 4; ++r) {
        float s = accS[ni][r] * 0.125f;
        if (diag && (ni * 16 + col) > (wave * 16 + quad * 4 + r)) s = -1e30f;
        sc[ni][r] = s;
      }

    #pragma unroll
    for (int r = 0; r < 4; ++r) {
      float cm = fmaxf(fmaxf(sc[0][r], sc[1][r]), fmaxf(sc[2][r], sc[3][r]));
      #pragma unroll
      for (int off = 1; off < 16; off <<= 1) cm = fmaxf(cm, __shfl_xor(cm, off));
      float mnew = fmaxf(mr[r], cm);
      float alpha = __expf(mr[r] - mnew);
      mr[r] = mnew;
      float ps = 0.f;
      #pragma unroll
      for (int ni = 0; ni < 4; ++ni) {
        float pv = __expf(sc[ni][r] - mnew);
        sc[ni][r] = pv;
        ps += pv;
      }
      #pragma unroll
      for (int off = 1; off < 16; off <<= 1) ps += __shfl_xor(ps, off);
      ls[r] = ls[r] * alpha + ps;
      #pragma unroll
      for (int ni = 0; ni < 4; ++ni) aO[ni][r] *= alpha;
    }

    #pragma unroll
    for (int ni = 0; ni < 4; ++ni)
      #pragma unroll
      for (int r = 0; r < 4; ++r) {
        int prow = quad * 4 + r;
        int pseg = ni * 2 + (col >> 3);
        Ps[wave][prow * 64 + ((pseg ^ (prow & 7)) << 3) + (col & 7)] =
            __float2bfloat16(sc[ni][r]);
      }

    #pragma unroll
    for (int kc = 0; kc < 2; ++kc) {
      bf16x8 ap = *reinterpret_cast<const bf16x8*>(&Ps[wave][swz(col, kc * 4 + quad)]);
      #pragma unroll
      for (int ni = 0; ni < 4; ++ni) {
        bf16x8 bv = *reinterpret_cast<const bf16x8*>(&Vt[swz(ni * 16 + col, kc * 4 + quad)]);
        aO[ni] = __builtin_amdgcn_mfma_f32_16x16x32_bf16(ap, bv, aO[ni], 0, 0, 0);
      }
    }
  };

  load_kv(0);
  for (int c = 0; c <= t1; ++c) {
    __syncthreads();
    store_kv();
    __syncthreads();
    if (c < t1) load_kv(c + 1);
    compute_tile(Qs[1], t1, c, mrow[1], lsum[1], accO[1]);
    if (c <= t0) compute_tile(Qs[0], t0, c, mrow[0], lsum[0], accO[0]);
  }

  #pragma unroll
  for (int t = 0; t < 2; ++t) {
    const int tq = t ? t1 : t0;
    float inv[4];
    #pragma unroll
    for (int r = 0; r < 4; ++r) inv[r] = 1.f / lsum[t][r];
    #pragma unroll
    for (int ni = 0; ni < 4; ++ni)
      #pragma unroll
      for (int r = 0; r < 4; ++r) {
        int qg = tq * 64 + wave * 16 + quad * 4 + r;
        o[((size_t)b * Ss + qg) * INNERi + h * 64 + ni * 16 + col] =
            __float2bfloat16(accO[t][ni][r] * inv[r]);
      }
  }
}

// ---------------------------------------------------------------------------
// Epilogue: out[b,d,sp] = x[b, 255+sp, d] — LDS-tiled transpose.
// grid: (256/32, 512/32, B), block (32,8).
// ---------------------------------------------------------------------------
__global__ void epilogue_kernel(const float* __restrict__ x, float* __restrict__ out)
{
  __shared__ float tile[32][33];
  int sp0 = blockIdx.x * 32, d0 = blockIdx.y * 32, b = blockIdx.z;
  int tx = threadIdx.x;
  #pragma unroll
  for (int i = threadIdx.y; i < 32; i += 8)
    tile[i][tx] = x[((size_t)b * Ss + (NCc - 1) + sp0 + i) * Dd + d0 + tx];
  __syncthreads();
  #pragma unroll
  for (int i = threadIdx.y; i < 32; i += 8)
    out[((size_t)b * Dd + d0 + i) * 256 + sp0 + tx] = tile[tx][i];
}

// ---------------------------------------------------------------------------
extern "C" void kernel_launch(void* const* d_in, const int* in_sizes, int n_in,
                              void* d_out, int out_size, void* d_ws, size_t ws_size,
                              hipStream_t stream)
{
  const float* z       = (const float*)d_in[0];
  const float* slots   = (const float*)d_in[1];
  const float* pos_emb = (const float*)d_in[2];
  const float* spos    = (const float*)d_in[3];
  const float* norm_w  = (const float*)d_in[4];
  const float* norm_b  = (const float*)d_in[5];
  const float* ln1_w   = (const float*)d_in[6];
  const float* ln1_b   = (const float*)d_in[7];
  const float* qkv_w   = (const float*)d_in[8];
  const float* out_w   = (const float*)d_in[9];
  const float* out_b   = (const float*)d_in[10];
  const float* ln2_w   = (const float*)d_in[11];
  const float* ln2_b   = (const float*)d_in[12];
  const float* mlp_w1  = (const float*)d_in[13];
  const float* mlp_b1  = (const float*)d_in[14];
  const float* mlp_w2  = (const float*)d_in[15];
  const float* mlp_b2  = (const float*)d_in[16];

  char* ws = (char*)d_ws;
  float*          xbuf = (float*)ws;
  __hip_bfloat16* ybuf = (__hip_bfloat16*)(ws + 33554432);
  __hip_bfloat16* qkvb = (__hip_bfloat16*)(ws + 50331648);
  __hip_bfloat16* obuf = (__hip_bfloat16*)(ws + 100663296);
  __hip_bfloat16* hbuf = (__hip_bfloat16*)(ws + 50331648);
  __hip_bfloat16* wT   = (__hip_bfloat16*)(ws + 117440512);

  const size_t WL = 3145728;

  dim3 tb(32, 8);
  transpose_w<<<dim3(1536 / 32, 512 / 32, 8), tb, 0, stream>>>(qkv_w,  wT + 0,       512, 1536, (size_t)512 * 1536, WL);
  transpose_w<<<dim3(512 / 32,  512 / 32, 8), tb, 0, stream>>>(out_w,  wT + 786432,  512, 512,  (size_t)512 * 512,  WL);
  transpose_w<<<dim3(2048 / 32, 512 / 32, 8), tb, 0, stream>>>(mlp_w1, wT + 1048576, 512, 2048, (size_t)512 * 2048, WL);
  transpose_w<<<dim3(512 / 32, 2048 / 32, 8), tb, 0, stream>>>(mlp_w2, wT + 2097152, 2048, 512, (size_t)2048 * 512, WL);

  prologue_kernel<<<Mrows, 64, 0, stream>>>(z, slots, pos_emb, spos, norm_w, norm_b, xbuf);

  for (int i = 0; i < 8; ++i) {
    const __hip_bfloat16* qkvT = wT + (size_t)i * WL;
    const __hip_bfloat16* outT = wT + (size_t)i * WL + 786432;
    const __hip_bfloat16* w1T  = wT + (size_t)i * WL + 1048576;
    const __hip_bfloat16* w2T  = wT + (size_t)i * WL + 2097152;

    ln_kernel<<<Mrows / 4, 256, 0, stream>>>(xbuf, ln1_w + i * Dd, ln1_b + i * Dd, ybuf);
    gemm_bt<0><<<dim3((1536 / 128) * (Mrows / 128)), 256, 0, stream>>>(
        ybuf, qkvT, nullptr, nullptr, qkvb, Mrows, 1536, 512);
    attn_pair<<<dim3(4, NHh, Bb), 256, 0, stream>>>(qkvb, obuf);
    gemm_bt<1><<<dim3((512 / 128) * (Mrows / 128)), 256, 0, stream>>>(
        obuf, outT, out_b + i * Dd, xbuf, xbuf, Mrows, 512, 512);
    ln_kernel<<<Mrows / 4, 256, 0, stream>>>(xbuf, ln2_w + i * Dd, ln2_b + i * Dd, ybuf);
    gemm_bt<2><<<dim3((2048 / 128) * (Mrows / 128)), 256, 0, stream>>>(
        ybuf, w1T, mlp_b1 + i * MLPm, nullptr, hbuf, Mrows, 2048, 512);
    gemm_bt<1><<<dim3((512 / 128) * (Mrows / 128)), 256, 0, stream>>>(
        hbuf, w2T, mlp_b2 + i * Dd, xbuf, xbuf, Mrows, 512, 2048);
  }

  epilogue_kernel<<<dim3(256 / 32, 512 / 32, Bb), tb, 0, stream>>>(xbuf, (float*)d_out);
}

// Round 9
// 1879.511 us; speedup vs baseline: 1.1235x; 1.0243x over previous
//
#include <hip/hip_runtime.h>
#include <hip/hip_bf16.h>
#include <math.h>

// Problem constants
#define Bb 32
#define Dd 512
#define Ss 512      // NC + Hs*Ws
#define NHh 8
#define DHh 64
#define MLPm 2048
#define NCc 256
#define INNERi 512
#define Mrows (Bb*Ss)   // 16384

typedef __bf16 bf16x8 __attribute__((ext_vector_type(8)));
typedef float floatx4 __attribute__((ext_vector_type(4)));

__device__ __forceinline__ void load_lds16(const void* g, void* l) {
  __builtin_amdgcn_global_load_lds(
      (__attribute__((address_space(1))) void*)(g),
      (__attribute__((address_space(3))) void*)(l), 16, 0, 0);
}

// XOR-swizzled LDS addressing for 64-elem bf16 rows: logical (row, seg8)
// stored at row*64 + ((seg ^ (row&7))<<3). b128 frag reads spread banks.
__device__ __forceinline__ int swz(int row, int seg) {
  return row * 64 + (((seg) ^ (row & 7)) << 3);
}

// Fast gelu: Abramowitz-Stegun 7.1.26 erf (|err| <= 1.5e-7, well below bf16
// output quantization) + __expf.
__device__ __forceinline__ float fast_gelu(float t) {
  float ax = fabsf(t) * 0.70710678118654752f;
  float u  = 1.0f / fmaf(0.3275911f, ax, 1.0f);
  float poly = u * fmaf(u, fmaf(u, fmaf(u, fmaf(u, 1.061405429f, -1.453152027f),
                                        1.421413741f), -0.284496736f), 0.254829592f);
  float erfv = 1.0f - poly * __expf(-ax * ax);
  erfv = copysignf(erfv, t);
  return 0.5f * t * (1.0f + erfv);
}

// ---------------------------------------------------------------------------
// Tiled transpose + fp32->bf16 downcast: in (K,N) fp32 -> out (N,K) bf16
// ---------------------------------------------------------------------------
__global__ void transpose_w(const float* __restrict__ in, __hip_bfloat16* __restrict__ out,
                            int K, int N, size_t in_ls, size_t out_ls)
{
  __shared__ float tile[32][33];
  in  += (size_t)blockIdx.z * in_ls;
  out += (size_t)blockIdx.z * out_ls;
  int n0 = blockIdx.x * 32, k0 = blockIdx.y * 32;
  int tx = threadIdx.x;
  #pragma unroll
  for (int i = threadIdx.y; i < 32; i += 8)
    tile[i][tx] = in[(size_t)(k0 + i) * N + n0 + tx];
  __syncthreads();
  #pragma unroll
  for (int i = threadIdx.y; i < 32; i += 8)
    out[(size_t)(n0 + i) * K + k0 + tx] = __float2bfloat16(tile[tx][i]);
}

// ---------------------------------------------------------------------------
// Prologue: build x[b,s,:] (slots+slot_pos | z^T+pos), then LayerNorm(norm_w/b)
// ---------------------------------------------------------------------------
__global__ void prologue_kernel(const float* __restrict__ z, const float* __restrict__ slots,
                                const float* __restrict__ pos, const float* __restrict__ spos,
                                const float* __restrict__ nw, const float* __restrict__ nb,
                                float* __restrict__ x)
{
  int row = blockIdx.x;            // b*S + s
  int b = row >> 9, s = row & 511;
  int lane = threadIdx.x;
  float v[8];
  float sum = 0.f;
  if (s < NCc) {
    const float4* s4 = reinterpret_cast<const float4*>(slots + ((size_t)b * NCc + s) * Dd) + lane * 2;
    const float4* p4 = reinterpret_cast<const float4*>(spos + (size_t)s * Dd) + lane * 2;
    float4 a0 = s4[0], a1 = s4[1], q0 = p4[0], q1 = p4[1];
    v[0] = a0.x + q0.x; v[1] = a0.y + q0.y; v[2] = a0.z + q0.z; v[3] = a0.w + q0.w;
    v[4] = a1.x + q1.x; v[5] = a1.y + q1.y; v[6] = a1.z + q1.z; v[7] = a1.w + q1.w;
    #pragma unroll
    for (int j = 0; j < 8; ++j) sum += v[j];
  } else {
    int sp = s - NCc;
    #pragma unroll
    for (int j = 0; j < 8; ++j) {
      int d = lane + j * 64;
      float t = z[((size_t)b * Dd + d) * 256 + sp] + pos[(size_t)sp * Dd + d];
      v[j] = t; sum += t;
    }
  }
  #pragma unroll
  for (int o = 32; o; o >>= 1) sum += __shfl_xor(sum, o);
  float mean = sum * (1.f / Dd);
  float vs = 0.f;
  #pragma unroll
  for (int j = 0; j < 8; ++j) { float d = v[j] - mean; vs += d * d; }
  #pragma unroll
  for (int o = 32; o; o >>= 1) vs += __shfl_xor(vs, o);
  float rs = rsqrtf(vs * (1.f / Dd) + 1e-5f);
  if (s < NCc) {
    const float4* w4 = reinterpret_cast<const float4*>(nw) + lane * 2;
    const float4* b4 = reinterpret_cast<const float4*>(nb) + lane * 2;
    float4 w0 = w4[0], w1 = w4[1], c0 = b4[0], c1 = b4[1];
    float4 o0, o1;
    o0.x = (v[0]-mean)*rs*w0.x + c0.x; o0.y = (v[1]-mean)*rs*w0.y + c0.y;
    o0.z = (v[2]-mean)*rs*w0.z + c0.z; o0.w = (v[3]-mean)*rs*w0.w + c0.w;
    o1.x = (v[4]-mean)*rs*w1.x + c1.x; o1.y = (v[5]-mean)*rs*w1.y + c1.y;
    o1.z = (v[6]-mean)*rs*w1.z + c1.z; o1.w = (v[7]-mean)*rs*w1.w + c1.w;
    float4* xo = reinterpret_cast<float4*>(x + (size_t)row * Dd) + lane * 2;
    xo[0] = o0; xo[1] = o1;
  } else {
    #pragma unroll
    for (int j = 0; j < 8; ++j) {
      int d = lane + j * 64;
      x[(size_t)row * Dd + d] = (v[j] - mean) * rs * nw[d] + nb[d];
    }
  }
}

// ---------------------------------------------------------------------------
// LayerNorm: x fp32 (rows,512) -> y bf16. Vectorized.
// ---------------------------------------------------------------------------
__global__ void ln_kernel(const float* __restrict__ x, const float* __restrict__ w,
                          const float* __restrict__ b, __hip_bfloat16* __restrict__ y)
{
  int row = blockIdx.x * 4 + (threadIdx.x >> 6);
  int lane = threadIdx.x & 63;
  const float4* xr = reinterpret_cast<const float4*>(x + (size_t)row * Dd) + lane * 2;
  float4 va = xr[0], vb = xr[1];
  float v[8] = {va.x, va.y, va.z, va.w, vb.x, vb.y, vb.z, vb.w};
  float sum = 0.f;
  #pragma unroll
  for (int j = 0; j < 8; ++j) sum += v[j];
  #pragma unroll
  for (int o = 32; o; o >>= 1) sum += __shfl_xor(sum, o);
  float mean = sum * (1.f / Dd);
  float vs = 0.f;
  #pragma unroll
  for (int j = 0; j < 8; ++j) { float d = v[j] - mean; vs += d * d; }
  #pragma unroll
  for (int o = 32; o; o >>= 1) vs += __shfl_xor(vs, o);
  float rs = rsqrtf(vs * (1.f / Dd) + 1e-5f);
  const float4* w4 = reinterpret_cast<const float4*>(w) + lane * 2;
  const float4* b4 = reinterpret_cast<const float4*>(b) + lane * 2;
  float4 w0 = w4[0], w1 = w4[1], c0 = b4[0], c1 = b4[1];
  float wv[8] = {w0.x, w0.y, w0.z, w0.w, w1.x, w1.y, w1.z, w1.w};
  float bv[8] = {c0.x, c0.y, c0.z, c0.w, c1.x, c1.y, c1.z, c1.w};
  union { bf16x8 v8; __hip_bfloat16 e[8]; } o;
  #pragma unroll
  for (int j = 0; j < 8; ++j)
    o.e[j] = __float2bfloat16((v[j] - mean) * rs * wv[j] + bv[j]);
  *reinterpret_cast<bf16x8*>(y + (size_t)row * Dd + lane * 8) = o.v8;
}

// ---------------------------------------------------------------------------
// bf16 MFMA GEMM: C(M,N) = A(M,K) @ Bt(N,K)^T  [+bias] [+res] [gelu]
// MODE 0: -> bf16 out (no bias);  MODE 1: -> f32 out = acc+bias+res;
// MODE 2: -> bf16 out = gelu(acc+bias)
//
// ROUND 9 (3rd attempt at the convoy-stagger experiment; r6 compile error,
// r7/r8 infra failures on the s_sleep variant): co-resident blocks on a CU
// are raw bids = c mod 256 (dispatcher round-robin); identical code => their
// stage->vmcnt(0)->barrier phases ALIGN, so the whole CU drains together and
// bursts together (MfmaUtil 24% with no pipe saturated, occupancy-neutral
// rounds 4/5). Stagger keyed on (bid>>8)&3 offsets co-resident blocks by
// ~0/512/1024/1536 cyc (~iteration period ~2.5k cyc) so one block's drain
// overlaps another's compute. Implemented as a counted s_nop loop (no
// s_sleep builtin — de-risks the r7/r8 container failures).
// ---------------------------------------------------------------------------
template <int MODE>
__global__ __launch_bounds__(256, 4)
void gemm_bt(const __hip_bfloat16* __restrict__ A, const __hip_bfloat16* __restrict__ Bt,
             const float* __restrict__ bias, const float* __restrict__ res,
             void* __restrict__ Out, int M, int N, int K)
{
  constexpr int BM = 128, BN = 128, BK = 64;
  __shared__ __align__(16) __hip_bfloat16 As[BM * BK];
  __shared__ __align__(16) __hip_bfloat16 Bs[BN * BK];
  const int tid = threadIdx.x;
  const int lane = tid & 63;
  const int wave = tid >> 6;

  // XCD-aware block swizzle (bid%8 -> XCD heuristic; neutral if mapping differs)
  const int NBLK = N >> 7;
  const int bid = blockIdx.x;
  const int xcd = bid & 7;
  const int j = bid >> 3;
  const int nb = j % NBLK;
  const int mt = xcd + ((j / NBLK) << 3);
  const int m0 = mt << 7;
  const int n0 = nb << 7;

  // phase stagger: desync co-resident blocks (bids differing by 256).
  // ~16 cyc per iteration (s_nop 7 + loop SALU) -> 0/~512/~1024/~1536 cyc.
  {
    const int stag = ((bid >> 8) & 3) * 32;
    for (int i = 0; i < stag; ++i) asm volatile("s_nop 7");
  }

  const int wm = (wave & 1) * 64;
  const int wn = (wave >> 1) * 64;
  const int quad = lane >> 4;
  const int lrow = lane & 15;

  floatx4 acc[4][4];
  #pragma unroll
  for (int i = 0; i < 4; ++i)
    #pragma unroll
    for (int jj = 0; jj < 4; ++jj) {
      floatx4 z4 = {0.f, 0.f, 0.f, 0.f};
      acc[i][jj] = z4;
    }

  for (int k0 = 0; k0 < K; k0 += BK) {
    // stage tiles via glds; LDS chunk c is lane-linear (DMA constraint), the
    // GLOBAL segment is XOR-permuted so the LDS layout lands swizzled.
    #pragma unroll
    for (int it = 0; it < 4; ++it) {
      int c = it * 256 + tid;
      int row = c >> 3, seg = (c & 7) ^ (row & 7);
      load_lds16(A + (size_t)(m0 + row) * K + k0 + seg * 8, As + c * 8);
    }
    #pragma unroll
    for (int it = 0; it < 4; ++it) {
      int c = it * 256 + tid;
      int row = c >> 3, seg = (c & 7) ^ (row & 7);
      load_lds16(Bt + (size_t)(n0 + row) * K + k0 + seg * 8, Bs + c * 8);
    }
    __syncthreads();

    #pragma unroll
    for (int k1 = 0; k1 < BK; k1 += 32) {
      const int s0 = k1 >> 3;   // 0 or 4
      bf16x8 a[4], b[4];
      #pragma unroll
      for (int i = 0; i < 4; ++i)
        a[i] = *reinterpret_cast<const bf16x8*>(&As[swz(wm + i * 16 + lrow, s0 + quad)]);
      #pragma unroll
      for (int i = 0; i < 4; ++i)
        b[i] = *reinterpret_cast<const bf16x8*>(&Bs[swz(wn + i * 16 + lrow, s0 + quad)]);
      #pragma unroll
      for (int mi = 0; mi < 4; ++mi)
        #pragma unroll
        for (int ni = 0; ni < 4; ++ni)
          acc[mi][ni] = __builtin_amdgcn_mfma_f32_16x16x32_bf16(a[mi], b[ni], acc[mi][ni], 0, 0, 0);
    }
    __syncthreads();
  }

  #pragma unroll
  for (int mi = 0; mi < 4; ++mi) {
    #pragma unroll
    for (int r = 0; r < 4; ++r) {
      int gm = m0 + wm + mi * 16 + quad * 4 + r;
      #pragma unroll
      for (int ni = 0; ni < 4; ++ni) {
        int gn = n0 + wn + ni * 16 + lrow;
        float v = acc[mi][ni][r];
        size_t oi = (size_t)gm * N + gn;
        if (MODE == 0) {
          ((__hip_bfloat16*)Out)[oi] = __float2bfloat16(v);
        } else if (MODE == 1) {
          ((float*)Out)[oi] = v + bias[gn] + res[oi];
        } else {
          ((__hip_bfloat16*)Out)[oi] = __float2bfloat16(fast_gelu(v + bias[gn]));
        }
      }
    }
  }
}

// ---------------------------------------------------------------------------
// Pair-balanced MFMA flash attention with XOR-swizzled LDS + reg prefetch.
// ---------------------------------------------------------------------------
__global__ __launch_bounds__(256, 2)
void attn_pair(const __hip_bfloat16* __restrict__ qkv, __hip_bfloat16* __restrict__ o)
{
  const int p = blockIdx.x;            // 0..3
  const int h = blockIdx.y, b = blockIdx.z;
  const int t0 = p, t1 = 7 - p;

  __shared__ __align__(16) __hip_bfloat16 Qs[2][64 * 64];
  __shared__ __align__(16) __hip_bfloat16 Ks[64 * 64];
  __shared__ __align__(16) __hip_bfloat16 Vt[64 * 64];   // (dh, key), swizzled
  __shared__ __align__(16) __hip_bfloat16 Ps[4][16 * 64];

  const int tid = threadIdx.x, lane = tid & 63, wave = tid >> 6;
  const int quad = lane >> 4, col = lane & 15;
  const size_t base = ((size_t)b * Ss) * 1536 + (size_t)h * 64;

  // stage Q for both tiles (swizzled)
  #pragma unroll
  for (int t = 0; t < 2; ++t) {
    const int tq = t ? t1 : t0;
    #pragma unroll
    for (int it = 0; it < 2; ++it) {
      int c = it * 256 + tid;
      int row = c >> 3, seg = c & 7;
      bf16x8 q8 = *reinterpret_cast<const bf16x8*>(
          qkv + base + (size_t)(tq * 64 + row) * 1536 + seg * 8);
      *reinterpret_cast<bf16x8*>(&Qs[t][swz(row, seg)]) = q8;
    }
  }

  bf16x8 kreg[2], vreg[2];
  auto load_kv = [&](int c0) {
    #pragma unroll
    for (int it = 0; it < 2; ++it) {
      int c = it * 256 + tid;
      kreg[it] = *reinterpret_cast<const bf16x8*>(
          qkv + base + 512 + (size_t)(c0 * 64 + (c >> 3)) * 1536 + (c & 7) * 8);
    }
    #pragma unroll
    for (int it = 0; it < 2; ++it) {
      int row = tid & 63, seg = it * 4 + wave;
      vreg[it] = *reinterpret_cast<const bf16x8*>(
          qkv + base + 1024 + (size_t)(c0 * 64 + row) * 1536 + seg * 8);
    }
  };
  auto store_kv = [&]() {
    #pragma unroll
    for (int it = 0; it < 2; ++it) {
      int c = it * 256 + tid;
      *reinterpret_cast<bf16x8*>(&Ks[swz(c >> 3, c & 7)]) = kreg[it];
    }
    #pragma unroll
    for (int it = 0; it < 2; ++it) {
      int row = tid & 63, seg = it * 4 + wave;
      union { bf16x8 v; __hip_bfloat16 e[8]; } u; u.v = vreg[it];
      #pragma unroll
      for (int j = 0; j < 8; ++j) {
        int d = seg * 8 + j;
        Vt[d * 64 + ((((row >> 3)) ^ (d & 7)) << 3) + (row & 7)] = u.e[j];
      }
    }
  };

  float  mrow[2][4], lsum[2][4];
  floatx4 accO[2][4];
  #pragma unroll
  for (int t = 0; t < 2; ++t)
    #pragma unroll
    for (int r = 0; r < 4; ++r) {
      mrow[t][r] = -1e30f; lsum[t][r] = 0.f;
      floatx4 z4 = {0.f, 0.f, 0.f, 0.f};
      accO[t][r] = z4;
    }

  auto compute_tile = [&](const __hip_bfloat16* Qt, int tq, int c,
                          float* mr, float* ls, floatx4* aO) {
    floatx4 accS[4];
    #pragma unroll
    for (int i = 0; i < 4; ++i) { floatx4 z4 = {0.f,0.f,0.f,0.f}; accS[i] = z4; }
    const int m = wave * 16 + col;
    #pragma unroll
    for (int kc = 0; kc < 2; ++kc) {
      bf16x8 aq = *reinterpret_cast<const bf16x8*>(&Qt[swz(m, kc * 4 + quad)]);
      #pragma unroll
      for (int ni = 0; ni < 4; ++ni) {
        bf16x8 bk = *reinterpret_cast<const bf16x8*>(&Ks[swz(ni * 16 + col, kc * 4 + quad)]);
        accS[ni] = __builtin_amdgcn_mfma_f32_16x16x32_bf16(aq, bk, accS[ni], 0, 0, 0);
      }
    }

    const bool diag = (c == tq);
    float sc[4][4];
    #pragma unroll
    for (int ni = 0; ni < 4; ++ni)
      #pragma unroll
      for (int r = 0; r < 4; ++r) {
        float s = accS[ni][r] * 0.125f;
        if (diag && (ni * 16 + col) > (wave * 16 + quad * 4 + r)) s = -1e30f;
        sc[ni][r] = s;
      }

    #pragma unroll
    for (int r = 0; r < 4; ++r) {
      float cm = fmaxf(fmaxf(sc[0][r], sc[1][r]), fmaxf(sc[2][r], sc[3][r]));
      #pragma unroll
      for (int off = 1; off < 16; off <<= 1) cm = fmaxf(cm, __shfl_xor(cm, off));
      float mnew = fmaxf(mr[r], cm);
      float alpha = __expf(mr[r] - mnew);
      mr[r] = mnew;
      float ps = 0.f;
      #pragma unroll
      for (int ni = 0; ni < 4; ++ni) {
        float pv = __expf(sc[ni][r] - mnew);
        sc[ni][r] = pv;
        ps += pv;
      }
      #pragma unroll
      for (int off = 1; off < 16; off <<= 1) ps += __shfl_xor(ps, off);
      ls[r] = ls[r] * alpha + ps;
      #pragma unroll
      for (int ni = 0; ni < 4; ++ni) aO[ni][r] *= alpha;
    }

    #pragma unroll
    for (int ni = 0; ni < 4; ++ni)
      #pragma unroll
      for (int r = 0; r < 4; ++r) {
        int prow = quad * 4 + r;
        int pseg = ni * 2 + (col >> 3);
        Ps[wave][prow * 64 + ((pseg ^ (prow & 7)) << 3) + (col & 7)] =
            __float2bfloat16(sc[ni][r]);
      }

    #pragma unroll
    for (int kc = 0; kc < 2; ++kc) {
      bf16x8 ap = *reinterpret_cast<const bf16x8*>(&Ps[wave][swz(col, kc * 4 + quad)]);
      #pragma unroll
      for (int ni = 0; ni < 4; ++ni) {
        bf16x8 bv = *reinterpret_cast<const bf16x8*>(&Vt[swz(ni * 16 + col, kc * 4 + quad)]);
        aO[ni] = __builtin_amdgcn_mfma_f32_16x16x32_bf16(ap, bv, aO[ni], 0, 0, 0);
      }
    }
  };

  load_kv(0);
  for (int c = 0; c <= t1; ++c) {
    __syncthreads();
    store_kv();
    __syncthreads();
    if (c < t1) load_kv(c + 1);
    compute_tile(Qs[1], t1, c, mrow[1], lsum[1], accO[1]);
    if (c <= t0) compute_tile(Qs[0], t0, c, mrow[0], lsum[0], accO[0]);
  }

  #pragma unroll
  for (int t = 0; t < 2; ++t) {
    const int tq = t ? t1 : t0;
    float inv[4];
    #pragma unroll
    for (int r = 0; r < 4; ++r) inv[r] = 1.f / lsum[t][r];
    #pragma unroll
    for (int ni = 0; ni < 4; ++ni)
      #pragma unroll
      for (int r = 0; r < 4; ++r) {
        int qg = tq * 64 + wave * 16 + quad * 4 + r;
        o[((size_t)b * Ss + qg) * INNERi + h * 64 + ni * 16 + col] =
            __float2bfloat16(accO[t][ni][r] * inv[r]);
      }
  }
}

// ---------------------------------------------------------------------------
// Epilogue: out[b,d,sp] = x[b, 255+sp, d] — LDS-tiled transpose.
// grid: (256/32, 512/32, B), block (32,8).
// ---------------------------------------------------------------------------
__global__ void epilogue_kernel(const float* __restrict__ x, float* __restrict__ out)
{
  __shared__ float tile[32][33];
  int sp0 = blockIdx.x * 32, d0 = blockIdx.y * 32, b = blockIdx.z;
  int tx = threadIdx.x;
  #pragma unroll
  for (int i = threadIdx.y; i < 32; i += 8)
    tile[i][tx] = x[((size_t)b * Ss + (NCc - 1) + sp0 + i) * Dd + d0 + tx];
  __syncthreads();
  #pragma unroll
  for (int i = threadIdx.y; i < 32; i += 8)
    out[((size_t)b * Dd + d0 + i) * 256 + sp0 + tx] = tile[tx][i];
}

// ---------------------------------------------------------------------------
extern "C" void kernel_launch(void* const* d_in, const int* in_sizes, int n_in,
                              void* d_out, int out_size, void* d_ws, size_t ws_size,
                              hipStream_t stream)
{
  const float* z       = (const float*)d_in[0];
  const float* slots   = (const float*)d_in[1];
  const float* pos_emb = (const float*)d_in[2];
  const float* spos    = (const float*)d_in[3];
  const float* norm_w  = (const float*)d_in[4];
  const float* norm_b  = (const float*)d_in[5];
  const float* ln1_w   = (const float*)d_in[6];
  const float* ln1_b   = (const float*)d_in[7];
  const float* qkv_w   = (const float*)d_in[8];
  const float* out_w   = (const float*)d_in[9];
  const float* out_b   = (const float*)d_in[10];
  const float* ln2_w   = (const float*)d_in[11];
  const float* ln2_b   = (const float*)d_in[12];
  const float* mlp_w1  = (const float*)d_in[13];
  const float* mlp_b1  = (const float*)d_in[14];
  const float* mlp_w2  = (const float*)d_in[15];
  const float* mlp_b2  = (const float*)d_in[16];

  char* ws = (char*)d_ws;
  float*          xbuf = (float*)ws;
  __hip_bfloat16* ybuf = (__hip_bfloat16*)(ws + 33554432);
  __hip_bfloat16* qkvb = (__hip_bfloat16*)(ws + 50331648);
  __hip_bfloat16* obuf = (__hip_bfloat16*)(ws + 100663296);
  __hip_bfloat16* hbuf = (__hip_bfloat16*)(ws + 50331648);
  __hip_bfloat16* wT   = (__hip_bfloat16*)(ws + 117440512);

  const size_t WL = 3145728;

  dim3 tb(32, 8);
  transpose_w<<<dim3(1536 / 32, 512 / 32, 8), tb, 0, stream>>>(qkv_w,  wT + 0,       512, 1536, (size_t)512 * 1536, WL);
  transpose_w<<<dim3(512 / 32,  512 / 32, 8), tb, 0, stream>>>(out_w,  wT + 786432,  512, 512,  (size_t)512 * 512,  WL);
  transpose_w<<<dim3(2048 / 32, 512 / 32, 8), tb, 0, stream>>>(mlp_w1, wT + 1048576, 512, 2048, (size_t)512 * 2048, WL);
  transpose_w<<<dim3(512 / 32, 2048 / 32, 8), tb, 0, stream>>>(mlp_w2, wT + 2097152, 2048, 512, (size_t)2048 * 512, WL);

  prologue_kernel<<<Mrows, 64, 0, stream>>>(z, slots, pos_emb, spos, norm_w, norm_b, xbuf);

  for (int i = 0; i < 8; ++i) {
    const __hip_bfloat16* qkvT = wT + (size_t)i * WL;
    const __hip_bfloat16* outT = wT + (size_t)i * WL + 786432;
    const __hip_bfloat16* w1T  = wT + (size_t)i * WL + 1048576;
    const __hip_bfloat16* w2T  = wT + (size_t)i * WL + 2097152;

    ln_kernel<<<Mrows / 4, 256, 0, stream>>>(xbuf, ln1_w + i * Dd, ln1_b + i * Dd, ybuf);
    gemm_bt<0><<<dim3((1536 / 128) * (Mrows / 128)), 256, 0, stream>>>(
        ybuf, qkvT, nullptr, nullptr, qkvb, Mrows, 1536, 512);
    attn_pair<<<dim3(4, NHh, Bb), 256, 0, stream>>>(qkvb, obuf);
    gemm_bt<1><<<dim3((512 / 128) * (Mrows / 128)), 256, 0, stream>>>(
        obuf, outT, out_b + i * Dd, xbuf, xbuf, Mrows, 512, 512);
    ln_kernel<<<Mrows / 4, 256, 0, stream>>>(xbuf, ln2_w + i * Dd, ln2_b + i * Dd, ybuf);
    gemm_bt<2><<<dim3((2048 / 128) * (Mrows / 128)), 256, 0, stream>>>(
        ybuf, w1T, mlp_b1 + i * MLPm, nullptr, hbuf, Mrows, 2048, 512);
    gemm_bt<1><<<dim3((512 / 128) * (Mrows / 128)), 256, 0, stream>>>(
        hbuf, w2T, mlp_b2 + i * Dd, xbuf, xbuf, Mrows, 512, 2048);
  }

  epilogue_kernel<<<dim3(256 / 32, 512 / 32, Bb), tb, 0, stream>>>(xbuf, (float*)d_out);
}